// Round 11
// baseline (466.963 us; speedup 1.0000x reference)
//
#include <hip/hip_runtime.h>
#include <hip/hip_bf16.h>
#include <stdint.h>

#define N_NODES 50000
#define N_EDGES 800000
#define K_KEEP  40000
#define BKT     196        // ceil(N_NODES/256) dst-range buckets
#define BCAP    6144       // per-bucket capacity (mean 4081, +32 sigma)

typedef unsigned long long u64;
typedef unsigned int u32;
typedef unsigned short u16;
typedef __hip_bfloat16 bf16;
typedef __hip_bfloat162 bf16x2;
typedef __attribute__((ext_vector_type(8))) short short8;
typedef __attribute__((ext_vector_type(4))) float f32x4;

struct Ctl {        // zeroed via hipMemsetAsync each call
  u64 prefix;
  u32 kremain;      // set to K_KEEP by init
  u32 cnt;
  float inv_norm;
  u32 isfp32;
  u32 done;
  u32 gen;          // generation counter for in-kernel radix passes
  u32 hist[256];
};

__device__ __forceinline__ float bf2f(bf16 v) { return __bfloat162float(v); }
__device__ __forceinline__ float loadF(const void* p, size_t i, bool f32) {
  return f32 ? ((const float*)p)[i] : bf2f(((const bf16*)p)[i]);
}
__device__ __forceinline__ short f2bf_bits(float f) {
  bf16 t = __float2bfloat16(f);
  return *(const short*)&t;
}

// -------- init + dtype detect + norm (last-block), ctl pre-zeroed --------

__global__ void init_norm_kernel(const unsigned short* __restrict__ x16,
                                 int* __restrict__ bucket_cur, int* __restrict__ detcnt,
                                 const void* __restrict__ pw, Ctl* ctl, int nblocks) {
  __shared__ u32 dsh[256];
  __shared__ int lastflag;
  const int tid = threadIdx.x;
  int i = blockIdx.x * 256 + tid;
  if (i < BKT) bucket_cur[i] = i * BCAP;
  if (blockIdx.x == 0 && tid == 0) ctl->kremain = K_KEEP;
  if (blockIdx.x < 64) {
    int base = blockIdx.x * 2048;
    u32 c = 0;
    for (int j = tid; j < 2048; j += 256) {
      u32 h = x16[base + j];
      if ((h & 0x7F80u) == 0x7F80u) c++;   // bf16 exp==0xFF => fp32 mantissa junk
    }
    dsh[tid] = c;
    __syncthreads();
    for (int s = 128; s > 0; s >>= 1) {
      if (tid < s) dsh[tid] += dsh[tid + s];
      __syncthreads();
    }
    if (tid == 0) atomicExch(&detcnt[blockIdx.x], (int)dsh[0]);
  }
  if (tid == 0) {
    __threadfence();
    u32 old = atomicAdd(&ctl->done, 1u);
    lastflag = (old == (u32)(nblocks - 1));
  }
  __syncthreads();
  if (!lastflag) return;
  if (tid < 64) {   // wave 0 computes norm + dtype flag
    int dc = atomicAdd(&detcnt[tid], 0);
    for (int off = 32; off; off >>= 1) dc += __shfl_down(dc, off);
    dc = __shfl(dc, 0);
    bool f32 = (dc >= 16);
    float v0 = loadF(pw, tid, f32);
    float v1 = loadF(pw, 64 + tid, f32);
    float s = v0 * v0 + v1 * v1;
    for (int off = 32; off; off >>= 1) s += __shfl_down(s, off);
    if (tid == 0) {
      ctl->inv_norm = 1.0f / sqrtf(s);
      ctl->isfp32 = f32 ? 1u : 0u;
      ctl->done = 0u;
    }
  }
}

// x -> bf16 (copy if already bf16)
__global__ void cvt_kernel(const void* __restrict__ x, u32* __restrict__ xb, const Ctl* __restrict__ ctl) {
  const bool f32 = ctl->isfp32 != 0;
  int p = blockIdx.x * 256 + threadIdx.x;   // pair index
  if (p >= N_NODES * 32) return;
  if (f32) {
    float2 v = ((const float2*)x)[p];
    xb[p] = ((u32)(u16)f2bf_bits(v.x)) | (((u32)(u16)f2bf_bits(v.y)) << 16);
  } else {
    xb[p] = ((const u32*)x)[p];
  }
}

// ------------- CSR1 via bucket sort (proven R8) -------------

__global__ void bucket_scatter_kernel(const int* __restrict__ src, const int* __restrict__ dst,
                                      int* __restrict__ bucket_cur, u32* __restrict__ bucketbuf)
{
  __shared__ u32 hist[BKT];
  __shared__ u32 base[BKT];
  const int tid = threadIdx.x;
  const int e0 = blockIdx.x * 2048;
  for (int t = tid; t < BKT; t += 256) hist[t] = 0;
  __syncthreads();
  #pragma unroll
  for (int j = 0; j < 8; ++j) {
    int e = e0 + j * 256 + tid;
    if (e < N_EDGES) atomicAdd(&hist[dst[e] >> 8], 1u);
  }
  __syncthreads();
  for (int t = tid; t < BKT; t += 256) {
    u32 c = hist[t];
    base[t] = c ? (u32)atomicAdd(&bucket_cur[t], (int)c) : 0u;
    hist[t] = 0;
  }
  __syncthreads();
  #pragma unroll
  for (int j = 0; j < 8; ++j) {
    int e = e0 + j * 256 + tid;
    if (e < N_EDGES) {
      int d = dst[e];
      int b = d >> 8;
      u32 pos = base[b] + atomicAdd(&hist[b], 1u);
      bucketbuf[pos] = ((u32)src[e] << 8) | (u32)(d & 255);
    }
  }
}

// per-block redundant scan of bucket sizes, then count/scan/fill window in LDS
__global__ void csr_from_buckets_kernel(const u32* __restrict__ bucketbuf, const int* __restrict__ bucket_cur,
                                        int* __restrict__ rowstart, float* __restrict__ dis,
                                        int* __restrict__ csr)
{
  __shared__ int sc[256];
  __shared__ u32 cnt[256];
  __shared__ u32 loc[256];
  __shared__ u32 cur[256];
  const int b = blockIdx.x;
  const int tid = threadIdx.x;
  int v = (tid < BKT) ? (bucket_cur[tid] - tid * BCAP) : 0;
  sc[tid] = v;
  __syncthreads();
  for (int off = 1; off < 256; off <<= 1) {
    int t = (tid >= off) ? sc[tid - off] : 0;
    __syncthreads();
    sc[tid] += t;
    __syncthreads();
  }
  const int off0 = (b == 0) ? 0 : sc[b - 1];
  if (b == 0 && tid == 0) rowstart[N_NODES] = sc[BKT - 1];
  const int bc = bucket_cur[b] - b * BCAP;
  const u32* buf = bucketbuf + (size_t)b * BCAP;
  cnt[tid] = 0;
  __syncthreads();
  for (int i = tid; i < bc; i += 256) atomicAdd(&cnt[buf[i] & 255u], 1u);
  __syncthreads();
  u32 c = cnt[tid];
  loc[tid] = c;
  __syncthreads();
  for (int off = 1; off < 256; off <<= 1) {
    u32 t = (tid >= off) ? loc[tid - off] : 0;
    __syncthreads();
    loc[tid] += t;
    __syncthreads();
  }
  int node = b * 256 + tid;
  u32 excl = loc[tid] - c;
  if (node < N_NODES) {
    rowstart[node] = off0 + (int)excl;
    dis[node] = rsqrtf(1.0f + (float)c);
  }
  cur[tid] = off0 + excl;
  __syncthreads();
  for (int i = tid; i < bc; i += 256) {
    u32 p = buf[i];
    u32 pos = atomicAdd(&cur[p & 255u], 1u);
    csr[pos] = (int)(p >> 8);
  }
}

// ---------------- graph2: fused reduce+scan (last-block), then scanout ----------------

__global__ void reduce_scan_kernel(const int* __restrict__ cnt, int* __restrict__ bsum,
                                   int* __restrict__ boff, int n, int* __restrict__ rowstart_n,
                                   Ctl* ctl)
{
  __shared__ int sh[256];
  __shared__ int lastflag;
  const int tid = threadIdx.x;
  int i = blockIdx.x * 256 + tid;
  sh[tid] = (i < n) ? cnt[i] : 0;
  __syncthreads();
  for (int s = 128; s > 0; s >>= 1) {
    if (tid < s) sh[tid] += sh[tid + s];
    __syncthreads();
  }
  if (tid == 0) {
    atomicExch(&bsum[blockIdx.x], sh[0]);
    __threadfence();
    u32 old = atomicAdd(&ctl->done, 1u);
    lastflag = (old == (u32)(gridDim.x - 1));
  }
  __syncthreads();
  if (!lastflag) return;
  int nb = gridDim.x;
  int v = (tid < nb) ? atomicAdd(&bsum[tid], 0) : 0;
  sh[tid] = v;
  __syncthreads();
  for (int off = 1; off < 256; off <<= 1) {
    int t = (tid >= off) ? sh[tid - off] : 0;
    __syncthreads();
    sh[tid] += t;
    __syncthreads();
  }
  if (tid < nb) boff[tid] = sh[tid] - v;
  if (tid == 255) *rowstart_n = sh[255];
  if (tid == 0) ctl->done = 0u;
}

__global__ void block_scanout_kernel(const int* __restrict__ cnt, const int* __restrict__ boff,
                                     int* __restrict__ rowstart, float* __restrict__ dis, int n) {
  __shared__ int sh[256];
  int tid = threadIdx.x;
  int i = blockIdx.x * 256 + tid;
  int c = (i < n) ? cnt[i] : 0;
  sh[tid] = c;
  __syncthreads();
  for (int off = 1; off < 256; off <<= 1) {
    int t = (tid >= off) ? sh[tid - off] : 0;
    __syncthreads();
    sh[tid] += t;
    __syncthreads();
  }
  if (i < n) {
    rowstart[i] = boff[blockIdx.x] + sh[tid] - c;
    dis[i] = rsqrtf(1.0f + (float)c);
  }
}

// ------- CSR2 from CSR1: filter-compact kept rows (proven R8) -------

__global__ void cnt2_kernel(const int* __restrict__ kept, const int* __restrict__ rowstart1,
                            const int* __restrict__ csr1, const int* __restrict__ new_idx,
                            int* __restrict__ cnt2)
{
  int gid = blockIdx.x * 256 + threadIdx.x;
  int kp = gid >> 4;
  int l16 = gid & 15;
  if (kp >= K_KEEP) return;
  int o = kept[kp];
  int i0 = rowstart1[o], i1 = rowstart1[o + 1];
  int c = 0;
  for (int i = i0 + l16; i < i1; i += 16) c += (new_idx[csr1[i]] >= 0);
  c += __shfl_down(c, 8, 16);
  c += __shfl_down(c, 4, 16);
  c += __shfl_down(c, 2, 16);
  c += __shfl_down(c, 1, 16);
  if (l16 == 0) cnt2[kp] = c;
}

__global__ void fill2_kernel(const int* __restrict__ kept, const int* __restrict__ rowstart1,
                             const int* __restrict__ csr1, const int* __restrict__ new_idx,
                             const int* __restrict__ rowstart2, int* __restrict__ csr2)
{
  int gid = blockIdx.x * 256 + threadIdx.x;
  int kp = gid >> 4;
  int l16 = gid & 15;
  if (kp >= K_KEEP) return;
  int o = kept[kp];
  int i0 = rowstart1[o], i1 = rowstart1[o + 1];
  int base = rowstart2[kp];
  int sub = (threadIdx.x & 63) >> 4;
  for (int ib = i0; ib < i1; ib += 16) {
    int i = ib + l16;
    int ns = -1;
    if (i < i1) ns = new_idx[csr1[i]];
    u64 bal = __ballot(ns >= 0);
    u32 m = (u32)((bal >> (sub * 16)) & 0xFFFFull);
    if (ns >= 0) {
      int rank = __popc(m & ((1u << l16) - 1u));
      csr2[base + rank] = ns;
    }
    base += __popc(m);
  }
}

// ------------- conv1 gather on bf16 input features; ILP-8 -------------

__global__ void agg_gather64_in_kernel(const bf16* __restrict__ xb, const int* __restrict__ rowstart,
                                       const int* __restrict__ csr, const float* __restrict__ dis,
                                       bf16* __restrict__ G, int M)
{
  int gid = blockIdx.x * 256 + threadIdx.x;
  int d = gid >> 6;
  int lane = gid & 63;
  if (d >= M) return;
  float dd = dis[d];
  float a = dd * dd * bf2f(xb[(size_t)d * 64 + lane]);
  int i = rowstart[d], i1 = rowstart[d + 1];
  for (; i + 8 <= i1; i += 8) {
    int s[8];
    #pragma unroll
    for (int j = 0; j < 8; ++j) s[j] = csr[i + j];
    float w[8];
    #pragma unroll
    for (int j = 0; j < 8; ++j) w[j] = dd * dis[s[j]];
    float v[8];
    #pragma unroll
    for (int j = 0; j < 8; ++j) v[j] = bf2f(xb[(size_t)s[j] * 64 + lane]);
    #pragma unroll
    for (int j = 0; j < 8; ++j) a += w[j] * v[j];
  }
  for (; i < i1; ++i) {
    int s = csr[i];
    a += dd * dis[s] * bf2f(xb[(size_t)s * 64 + lane]);
  }
  G[(size_t)d * 64 + lane] = __float2bfloat16(a);
}

// ---------------- MFMA GEMMs (16x16x32 bf16, fp32 acc; proven R9) ----------------

// conv1: Y[N,128] = G[N,64] @ W1 + b1, fused pooling score/keys
__global__ void gemm_in_kernel(const bf16* __restrict__ G, const void* __restrict__ W,
                               const void* __restrict__ b, const void* __restrict__ pw,
                               bf16* __restrict__ Y, const Ctl* __restrict__ ctl,
                               float* __restrict__ score, u64* __restrict__ keys)
{
  __shared__ short Xs[64 * 72];
  __shared__ short Wt[128 * 72];
  __shared__ float bs[128];
  __shared__ float ps[128];
  const bool f32 = ctl->isfp32 != 0;
  const int tid = threadIdx.x;
  const int row0 = blockIdx.x * 64;

  for (int i = tid; i < 64 * 128; i += 256) {
    int k = i >> 7, n = i & 127;
    Wt[n * 72 + k] = f32 ? f2bf_bits(((const float*)W)[i]) : ((const short*)W)[i];
  }
  const u32* G2 = (const u32*)G;
  for (int p = tid; p < 64 * 32; p += 256) {
    int r = p >> 5, kp = p & 31;
    int gr = row0 + r;
    u32 v = (gr < N_NODES) ? G2[(size_t)gr * 32 + kp] : 0u;
    *(u32*)&Xs[r * 72 + 2 * kp] = v;
  }
  for (int i = tid; i < 128; i += 256) { bs[i] = loadF(b, i, f32); ps[i] = loadF(pw, i, f32); }
  __syncthreads();

  const int lane = tid & 63;
  const int w = tid >> 6;
  const int l16 = lane & 15;
  const int quad = lane >> 4;
  f32x4 acc[8];
  #pragma unroll
  for (int ct = 0; ct < 8; ++ct) acc[ct] = (f32x4){0.f, 0.f, 0.f, 0.f};
  const int arow = w * 16 + l16;
  #pragma unroll
  for (int kc = 0; kc < 2; ++kc) {
    short8 a = *(short8*)&Xs[arow * 72 + kc * 32 + quad * 8];
    #pragma unroll
    for (int ct = 0; ct < 8; ++ct) {
      short8 bb = *(short8*)&Wt[(ct * 16 + l16) * 72 + kc * 32 + quad * 8];
      acc[ct] = __builtin_amdgcn_mfma_f32_16x16x32_bf16(a, bb, acc[ct], 0, 0, 0);
    }
  }
  float inv_norm = ctl->inv_norm;
  #pragma unroll
  for (int r = 0; r < 4; ++r) {
    int gr = row0 + w * 16 + quad * 4 + r;
    float p = 0.f;
    #pragma unroll
    for (int ct = 0; ct < 8; ++ct) {
      int col = ct * 16 + l16;
      float h = acc[ct][r] + bs[col];
      if (gr < N_NODES) Y[(size_t)gr * 128 + col] = __float2bfloat16(h);
      p += fmaxf(h, 0.f) * ps[col];
    }
    p += __shfl_down(p, 8, 16);
    p += __shfl_down(p, 4, 16);
    p += __shfl_down(p, 2, 16);
    p += __shfl_down(p, 1, 16);
    if (l16 == 0 && gr < N_NODES) {
      float sc = tanhf(p * inv_norm);
      score[gr] = sc;
      u32 u = __float_as_uint(sc);
      u = (u & 0x80000000u) ? ~u : (u | 0x80000000u);
      keys[gr] = (((u64)u) << 16) | (u64)(0xFFFFu - (u32)gr);
    }
  }
}

// conv2 fused: Y[K,64] = (relu(h1[kept[r]])*score[kept[r]]) @ W2
__global__ void gemm_hp_128_64_kernel(const bf16* __restrict__ X, const int* __restrict__ kept,
                                      const float* __restrict__ score, const void* __restrict__ W,
                                      bf16* __restrict__ Y, const Ctl* __restrict__ ctl, int M)
{
  __shared__ short Xs[64 * 136];
  __shared__ short Wt[64 * 136];
  const bool f32 = ctl->isfp32 != 0;
  const int tid = threadIdx.x;
  const int row0 = blockIdx.x * 64;

  for (int i = tid; i < 128 * 64; i += 256) {
    int k = i >> 6, n = i & 63;
    Wt[n * 136 + k] = f32 ? f2bf_bits(((const float*)W)[i]) : ((const short*)W)[i];
  }
  const u32* X2 = (const u32*)X;
  for (int p = tid; p < 64 * 64; p += 256) {
    int r = p >> 6, kp = p & 63;
    int o = kept[row0 + r];
    float s = score[o];
    u32 v = X2[(size_t)o * 64 + kp];
    bf16x2 h = *(bf16x2*)&v;
    float vx = fmaxf(bf2f(h.x), 0.f) * s;
    float vy = fmaxf(bf2f(h.y), 0.f) * s;
    Xs[r * 136 + 2 * kp]     = f2bf_bits(vx);
    Xs[r * 136 + 2 * kp + 1] = f2bf_bits(vy);
  }
  __syncthreads();

  const int lane = tid & 63;
  const int w = tid >> 6;
  const int l16 = lane & 15;
  const int quad = lane >> 4;
  f32x4 acc[4];
  #pragma unroll
  for (int ct = 0; ct < 4; ++ct) acc[ct] = (f32x4){0.f, 0.f, 0.f, 0.f};
  const int arow = w * 16 + l16;
  #pragma unroll
  for (int kc = 0; kc < 4; ++kc) {
    short8 a = *(short8*)&Xs[arow * 136 + kc * 32 + quad * 8];
    #pragma unroll
    for (int ct = 0; ct < 4; ++ct) {
      short8 bb = *(short8*)&Wt[(ct * 16 + l16) * 136 + kc * 32 + quad * 8];
      acc[ct] = __builtin_amdgcn_mfma_f32_16x16x32_bf16(a, bb, acc[ct], 0, 0, 0);
    }
  }
  #pragma unroll
  for (int ct = 0; ct < 4; ++ct)
    #pragma unroll
    for (int r = 0; r < 4; ++r) {
      int gr = row0 + w * 16 + quad * 4 + r;
      Y[(size_t)gr * 64 + ct * 16 + l16] = __float2bfloat16(acc[ct][r]);
    }
}

// conv4: Y[M,64] = relu(X[M,128]) @ W[128,64]
__global__ void gemm_128_64_kernel(const bf16* __restrict__ X, const void* __restrict__ W,
                                   bf16* __restrict__ Y, const Ctl* __restrict__ ctl,
                                   int M, int relu_x)
{
  __shared__ short Xs[64 * 136];
  __shared__ short Wt[64 * 136];
  const bool f32 = ctl->isfp32 != 0;
  const int tid = threadIdx.x;
  const int row0 = blockIdx.x * 64;

  for (int i = tid; i < 128 * 64; i += 256) {
    int k = i >> 6, n = i & 63;
    Wt[n * 136 + k] = f32 ? f2bf_bits(((const float*)W)[i]) : ((const short*)W)[i];
  }
  const u32* X2 = (const u32*)X;
  for (int p = tid; p < 64 * 64; p += 256) {
    int r = p >> 6, kp = p & 63;
    u32 v = X2[(size_t)(row0 + r) * 64 + kp];
    if (relu_x) {
      if (v & 0x8000u) v &= 0xFFFF0000u;
      if (v & 0x80000000u) v &= 0x0000FFFFu;
    }
    *(u32*)&Xs[r * 136 + 2 * kp] = v;
  }
  __syncthreads();

  const int lane = tid & 63;
  const int w = tid >> 6;
  const int l16 = lane & 15;
  const int quad = lane >> 4;
  f32x4 acc[4];
  #pragma unroll
  for (int ct = 0; ct < 4; ++ct) acc[ct] = (f32x4){0.f, 0.f, 0.f, 0.f};
  const int arow = w * 16 + l16;
  #pragma unroll
  for (int kc = 0; kc < 4; ++kc) {
    short8 a = *(short8*)&Xs[arow * 136 + kc * 32 + quad * 8];
    #pragma unroll
    for (int ct = 0; ct < 4; ++ct) {
      short8 bb = *(short8*)&Wt[(ct * 16 + l16) * 136 + kc * 32 + quad * 8];
      acc[ct] = __builtin_amdgcn_mfma_f32_16x16x32_bf16(a, bb, acc[ct], 0, 0, 0);
    }
  }
  #pragma unroll
  for (int ct = 0; ct < 4; ++ct)
    #pragma unroll
    for (int r = 0; r < 4; ++r) {
      int gr = row0 + w * 16 + quad * 4 + r;
      Y[(size_t)gr * 64 + ct * 16 + l16] = __float2bfloat16(acc[ct][r]);
    }
}

// conv3: Y[M,128] = X[M,64] @ W[64,128] + b
__global__ void gemm_64_128_kernel(const bf16* __restrict__ X, const void* __restrict__ W,
                                   const void* __restrict__ b, bf16* __restrict__ Y,
                                   const Ctl* __restrict__ ctl, int M)
{
  __shared__ short Xs[64 * 72];
  __shared__ short Wt[128 * 72];
  __shared__ float bs[128];
  const bool f32 = ctl->isfp32 != 0;
  const int tid = threadIdx.x;
  const int row0 = blockIdx.x * 64;

  for (int i = tid; i < 64 * 128; i += 256) {
    int k = i >> 7, n = i & 127;
    Wt[n * 72 + k] = f32 ? f2bf_bits(((const float*)W)[i]) : ((const short*)W)[i];
  }
  const u32* X2 = (const u32*)X;
  for (int p = tid; p < 64 * 32; p += 256) {
    int r = p >> 5, kp = p & 31;
    *(u32*)&Xs[r * 72 + 2 * kp] = X2[(size_t)(row0 + r) * 32 + kp];
  }
  for (int i = tid; i < 128; i += 256) bs[i] = loadF(b, i, f32);
  __syncthreads();

  const int lane = tid & 63;
  const int w = tid >> 6;
  const int l16 = lane & 15;
  const int quad = lane >> 4;
  f32x4 acc[8];
  #pragma unroll
  for (int ct = 0; ct < 8; ++ct) acc[ct] = (f32x4){0.f, 0.f, 0.f, 0.f};
  const int arow = w * 16 + l16;
  #pragma unroll
  for (int kc = 0; kc < 2; ++kc) {
    short8 a = *(short8*)&Xs[arow * 72 + kc * 32 + quad * 8];
    #pragma unroll
    for (int ct = 0; ct < 8; ++ct) {
      short8 bb = *(short8*)&Wt[(ct * 16 + l16) * 72 + kc * 32 + quad * 8];
      acc[ct] = __builtin_amdgcn_mfma_f32_16x16x32_bf16(a, bb, acc[ct], 0, 0, 0);
    }
  }
  #pragma unroll
  for (int ct = 0; ct < 8; ++ct)
    #pragma unroll
    for (int r = 0; r < 4; ++r) {
      int gr = row0 + w * 16 + quad * 4 + r;
      int col = ct * 16 + l16;
      Y[(size_t)gr * 128 + col] = __float2bfloat16(acc[ct][r] + bs[col]);
    }
}

// --------- gather on bf16 rows (64 ch), optional relu/bias; ILP-8 ---------

__global__ void agg_gather64_kernel(const bf16* __restrict__ hW, const int* __restrict__ rowstart,
                                    const int* __restrict__ csr, const float* __restrict__ dis,
                                    const void* __restrict__ b, const Ctl* __restrict__ ctl,
                                    bf16* __restrict__ agg, int M, int relusrc, int addbias)
{
  const bool f32 = ctl->isfp32 != 0;
  int gid = blockIdx.x * 256 + threadIdx.x;
  int d = gid >> 6;
  int lane = gid & 63;
  if (d >= M) return;
  float dd = dis[d];
  float v = bf2f(hW[(size_t)d * 64 + lane]);
  if (relusrc) v = fmaxf(v, 0.f);
  float a = v * dd * dd + (addbias ? loadF(b, lane, f32) : 0.f);
  int i = rowstart[d], i1 = rowstart[d + 1];
  for (; i + 8 <= i1; i += 8) {
    int s[8];
    #pragma unroll
    for (int j = 0; j < 8; ++j) s[j] = csr[i + j];
    float w[8];
    #pragma unroll
    for (int j = 0; j < 8; ++j) w[j] = dd * dis[s[j]];
    float vv[8];
    #pragma unroll
    for (int j = 0; j < 8; ++j) vv[j] = bf2f(hW[(size_t)s[j] * 64 + lane]);
    if (relusrc) {
      #pragma unroll
      for (int j = 0; j < 8; ++j) vv[j] = fmaxf(vv[j], 0.f);
    }
    #pragma unroll
    for (int j = 0; j < 8; ++j) a += w[j] * vv[j];
  }
  for (; i < i1; ++i) {
    int s = csr[i];
    float vv = bf2f(hW[(size_t)s * 64 + lane]);
    if (relusrc) vv = fmaxf(vv, 0.f);
    a += dd * dis[s] * vv;
  }
  agg[(size_t)d * 64 + lane] = __float2bfloat16(a);
}

// conv4: gather + bias + per-block mean-pool partial (plain stores); ILP-8
__global__ void agg_gather64_final_kernel(const bf16* __restrict__ hW, const int* __restrict__ rowstart,
                                          const int* __restrict__ csr, const float* __restrict__ dis,
                                          const void* __restrict__ b, const Ctl* __restrict__ ctl,
                                          float* __restrict__ partial, int M)
{
  __shared__ float cs[64];
  const bool f32 = ctl->isfp32 != 0;
  int tid = threadIdx.x;
  if (tid < 64) cs[tid] = 0.f;
  __syncthreads();
  int gid = blockIdx.x * 256 + tid;
  int d = gid >> 6;
  int lane = gid & 63;
  if (d < M) {
    float dd = dis[d];
    float a = bf2f(hW[(size_t)d * 64 + lane]) * (dd * dd) + loadF(b, lane, f32);
    int i = rowstart[d], i1 = rowstart[d + 1];
    for (; i + 8 <= i1; i += 8) {
      int s[8];
      #pragma unroll
      for (int j = 0; j < 8; ++j) s[j] = csr[i + j];
      float w[8];
      #pragma unroll
      for (int j = 0; j < 8; ++j) w[j] = dd * dis[s[j]];
      float vv[8];
      #pragma unroll
      for (int j = 0; j < 8; ++j) vv[j] = bf2f(hW[(size_t)s[j] * 64 + lane]);
      #pragma unroll
      for (int j = 0; j < 8; ++j) a += w[j] * vv[j];
    }
    for (; i < i1; ++i) {
      int s = csr[i];
      a += dd * dis[s] * bf2f(hW[(size_t)s * 64 + lane]);
    }
    atomicAdd(&cs[lane], a);
  }
  __syncthreads();
  if (tid < 64) partial[(size_t)tid * gridDim.x + blockIdx.x] = cs[tid];
}

__global__ void reduce_out_kernel(const float* __restrict__ partial, const Ctl* __restrict__ ctl,
                                  void* __restrict__ out, int nblk)
{
  __shared__ float sh[256];
  int c = blockIdx.x;
  float s = 0.f;
  for (int j = threadIdx.x; j < nblk; j += 256) s += partial[(size_t)c * nblk + j];
  sh[threadIdx.x] = s;
  __syncthreads();
  for (int st = 128; st > 0; st >>= 1) {
    if (threadIdx.x < st) sh[threadIdx.x] += sh[threadIdx.x + st];
    __syncthreads();
  }
  if (threadIdx.x == 0) {
    float val = sh[0] / (float)K_KEEP;
    if (ctl->isfp32) ((float*)out)[c] = val;
    else             ((bf16*)out)[c] = __float2bfloat16(val);
  }
}

// ------------- Fused top-K: 6 radix passes + mark, ONE kernel -------------
// 196 blocks (all co-resident on 256 CUs; graph stream runs nothing else).
// Cross-block state via device-scope atomics only (per-XCD L2 non-coherence).

__global__ void topk_kernel(const u64* __restrict__ keys, Ctl* ctl,
                            int* __restrict__ new_idx, int* __restrict__ kept, int nblocks)
{
  __shared__ u32 lh[256];
  __shared__ int lastflag;
  __shared__ u64 sprefix;
  const int tid = threadIdx.x;
  const int i = blockIdx.x * 256 + tid;
  const u64 key = (i < N_NODES) ? keys[i] : 0ull;
  u64 prefix = 0ull;

  for (int p = 0; p < 6; ++p) {
    const int shift = 40 - 8 * p;
    lh[tid] = 0;
    __syncthreads();
    if (i < N_NODES && (key >> (shift + 8)) == (prefix >> (shift + 8)))
      atomicAdd(&lh[(u32)((key >> shift) & 0xFF)], 1u);
    __syncthreads();
    u32 c = lh[tid];
    if (c) atomicAdd(&ctl->hist[tid], c);
    __syncthreads();
    if (tid == 0) {
      __threadfence();
      u32 old = atomicAdd(&ctl->done, 1u);
      lastflag = (old == (u32)(nblocks - 1));
    }
    __syncthreads();
    if (lastflag) {
      lh[tid] = atomicExch(&ctl->hist[tid], 0u);
      __syncthreads();
      if (tid == 0) {
        u32 kr = atomicAdd(&ctl->kremain, 0u);
        u32 cum = 0;
        int sel = 0;
        for (int v = 255; v >= 0; --v) {
          u32 cc = lh[v];
          if (cum + cc >= kr) { sel = v; break; }
          cum += cc;
        }
        u64 np = prefix | (((u64)sel) << shift);
        atomicExch(&ctl->prefix, np);
        atomicExch(&ctl->kremain, kr - cum);
        atomicExch(&ctl->done, 0u);
        __threadfence();
        atomicAdd(&ctl->gen, 1u);
      }
    }
    if (tid == 0) {
      while (atomicAdd(&ctl->gen, 0u) < (u32)(p + 1)) __builtin_amdgcn_s_sleep(16);
      __threadfence();
      sprefix = atomicAdd(&ctl->prefix, 0ull);
    }
    __syncthreads();
    prefix = sprefix;
  }

  // mark phase (block-aggregated; 1 global atomic per block)
  __shared__ u32 cnts[4];
  __shared__ u32 wbase[4];
  bool sel = (i < N_NODES) && (key >= prefix);
  u64 bal = __ballot(sel);
  int lane = tid & 63;
  int w = tid >> 6;
  if (lane == 0) cnts[w] = (u32)__popcll(bal);
  __syncthreads();
  if (tid == 0) {
    u32 tot = cnts[0] + cnts[1] + cnts[2] + cnts[3];
    u32 base = atomicAdd(&ctl->cnt, tot);
    wbase[0] = base;
    wbase[1] = base + cnts[0];
    wbase[2] = base + cnts[0] + cnts[1];
    wbase[3] = base + cnts[0] + cnts[1] + cnts[2];
  }
  __syncthreads();
  if (i < N_NODES) {
    if (sel) {
      int pos = (int)(wbase[w] + (u32)__popcll(bal & ((1ull << lane) - 1ull)));
      new_idx[i] = pos;
      kept[pos] = i;
    } else {
      new_idx[i] = -1;
    }
  }
}

// ---------------- launch ----------------

extern "C" void kernel_launch(void* const* d_in, const int* in_sizes, int n_in,
                              void* d_out, int out_size, void* d_ws, size_t ws_size,
                              hipStream_t stream)
{
  const void* x  = d_in[0];
  const int*  ei = (const int*)d_in[1];
  const void* W1 = d_in[3];
  const void* b1 = d_in[4];
  const void* pw = d_in[5];
  const void* W2 = d_in[6];
  const void* b2 = d_in[7];
  const void* W3 = d_in[8];
  const void* b3 = d_in[9];
  const void* W4 = d_in[10];
  const void* b4 = d_in[11];

  const int* src = ei;
  const int* dst = ei + N_EDGES;

  float* F = (float*)d_ws;
  bf16*  A16       = (bf16*)F;               // N x 128 bf16
  bf16*  B16       = (bf16*)(F + 3200000);   // N x 128 bf16
  bf16*  C16       = (bf16*)(F + 6400000);   // K x 128 bf16 (conv1 G / h2)
  float* dis1      = F + 9000000;            // 50000
  float* dis2      = F + 9050000;            // 40000
  float* score     = F + 9100000;            // 50000
  u64*   keys      = (u64*)(F + 9150000);    // 50000 u64
  int*   new_idx   = (int*)(F + 9250000);    // 50000
  int*   kept      = (int*)(F + 9300000);    // 40000
  int*   cnt2      = (int*)(F + 9340000);    // 40000
  int*   rowstart1 = (int*)(F + 9380000);    // 50001
  int*   rowstart2 = (int*)(F + 9430004);    // 40001
  int*   csr1      = (int*)(F + 9470008);    // 800000
  int*   csr2      = (int*)(F + 10270008);   // 800000
  Ctl*   ctl       = (Ctl*)(F + 11070008);   // ~1.1 KB
  int*   bsum      = (int*)(F + 11070500);   // 256
  int*   boff      = (int*)(F + 11070756);   // 256
  int*   detcnt    = (int*)(F + 11071012);   // 64
  int*   bucket_cur= (int*)(F + 11071076);   // 196
  u32*   bucketbuf = (u32*)(F + 11071332);   // 196*6144
  float* partial   = F + 12275556;           // 64 x 10000
  bf16*  xb16      = (bf16*)(F + 12915556);  // N x 64 bf16

  const int NB1 = (N_NODES + 255) / 256;     // 196
  const int NB2 = (K_KEEP + 255) / 256;      // 157
  const int EB2 = (N_EDGES + 2047) / 2048;   // 391
  const int SGB = (K_KEEP * 16 + 255) / 256; // 2500
  const int GFB = K_KEEP / 4;                // 10000

  hipMemsetAsync(ctl, 0, sizeof(Ctl), stream);
  init_norm_kernel<<<NB1, 256, 0, stream>>>((const unsigned short*)x, bucket_cur, detcnt, pw, ctl, NB1);
  cvt_kernel<<<(N_NODES * 32 + 255) / 256, 256, 0, stream>>>(x, (u32*)xb16, ctl);

  // CSR graph 1 via bucket sort
  bucket_scatter_kernel<<<EB2, 256, 0, stream>>>(src, dst, bucket_cur, bucketbuf);
  csr_from_buckets_kernel<<<BKT, 256, 0, stream>>>(bucketbuf, bucket_cur, rowstart1, dis1, csr1);

  // conv1 (gather-first): G = A_norm . x ; h1 = G @ W1 + b1 (+fused score)
  agg_gather64_in_kernel<<<(N_NODES + 3) / 4, 256, 0, stream>>>(xb16, rowstart1, csr1, dis1, C16, N_NODES);
  gemm_in_kernel<<<(N_NODES + 63) / 64, 256, 0, stream>>>(C16, W1, b1, pw, B16, ctl, score, keys);

  // fused top-K select (6 radix passes + mark, one kernel)
  topk_kernel<<<NB1, 256, 0, stream>>>(keys, ctl, new_idx, kept, NB1);

  // CSR graph 2: filter-compact kept rows of csr1
  cnt2_kernel<<<SGB, 256, 0, stream>>>(kept, rowstart1, csr1, new_idx, cnt2);
  reduce_scan_kernel<<<NB2, 256, 0, stream>>>(cnt2, bsum, boff, K_KEEP, &rowstart2[K_KEEP], ctl);
  block_scanout_kernel<<<NB2, 256, 0, stream>>>(cnt2, boff, rowstart2, dis2, K_KEEP);
  fill2_kernel<<<SGB, 256, 0, stream>>>(kept, rowstart1, csr1, new_idx, rowstart2, csr2);

  // conv2 (hp fused into gemm): A = (relu(h1[kept])*score) @ W2 ; h2 = gather(A) + b2
  gemm_hp_128_64_kernel<<<K_KEEP / 64, 256, 0, stream>>>(B16, kept, score, W2, A16, ctl, K_KEEP);
  agg_gather64_kernel<<<K_KEEP / 4, 256, 0, stream>>>(A16, rowstart2, csr2, dis2, b2, ctl, C16, K_KEEP, 0, 1);

  // conv3: gather-first: G = gather(relu(h2)) ; h3 = G @ W3 + b3
  agg_gather64_kernel<<<K_KEEP / 4, 256, 0, stream>>>(C16, rowstart2, csr2, dis2, b3, ctl, A16, K_KEEP, 1, 0);
  gemm_64_128_kernel<<<K_KEEP / 64, 256, 0, stream>>>(A16, W3, b3, B16, ctl, K_KEEP);

  // conv4: gemm-first: A = relu(h3) @ W4 ; partials = gather(A) + b4
  gemm_128_64_kernel<<<K_KEEP / 64, 256, 0, stream>>>(B16, W4, A16, ctl, K_KEEP, 1);
  agg_gather64_final_kernel<<<GFB, 256, 0, stream>>>(A16, rowstart2, csr2, dis2, b4, ctl, partial, K_KEEP);

  reduce_out_kernel<<<64, 256, 0, stream>>>(partial, ctl, d_out, GFB);
}

// Round 12
// 435.392 us; speedup vs baseline: 1.0725x; 1.0725x over previous
//
#include <hip/hip_runtime.h>
#include <hip/hip_bf16.h>
#include <stdint.h>

#define N_NODES 50000
#define N_EDGES 800000
#define K_KEEP  40000
#define BKT     196        // ceil(N_NODES/256) dst-range buckets
#define BCAP    6144       // per-bucket capacity (mean 4081, +32 sigma)

typedef unsigned long long u64;
typedef unsigned int u32;
typedef unsigned short u16;
typedef __hip_bfloat16 bf16;
typedef __hip_bfloat162 bf16x2;
typedef __attribute__((ext_vector_type(8))) short short8;
typedef __attribute__((ext_vector_type(4))) float f32x4;

struct Ctl {        // zeroed via hipMemsetAsync each call
  u64 prefix;
  u32 kremain;      // set to K_KEEP by init
  u32 cnt;
  float inv_norm;
  u32 isfp32;
  u32 done;
  u32 gen;
  u32 hist[256];
};

__device__ __forceinline__ float bf2f(bf16 v) { return __bfloat162float(v); }
__device__ __forceinline__ float loadF(const void* p, size_t i, bool f32) {
  return f32 ? ((const float*)p)[i] : bf2f(((const bf16*)p)[i]);
}
__device__ __forceinline__ short f2bf_bits(float f) {
  bf16 t = __float2bfloat16(f);
  return *(const short*)&t;
}

// -------- init + dtype detect + norm (last-block), ctl pre-zeroed --------

__global__ void init_norm_kernel(const unsigned short* __restrict__ x16,
                                 int* __restrict__ bucket_cur, int* __restrict__ detcnt,
                                 const void* __restrict__ pw, Ctl* ctl, int nblocks) {
  __shared__ u32 dsh[256];
  __shared__ int lastflag;
  const int tid = threadIdx.x;
  int i = blockIdx.x * 256 + tid;
  if (i < BKT) bucket_cur[i] = i * BCAP;
  if (blockIdx.x == 0 && tid == 0) ctl->kremain = K_KEEP;
  if (blockIdx.x < 64) {
    int base = blockIdx.x * 2048;
    u32 c = 0;
    for (int j = tid; j < 2048; j += 256) {
      u32 h = x16[base + j];
      if ((h & 0x7F80u) == 0x7F80u) c++;   // bf16 exp==0xFF => fp32 mantissa junk
    }
    dsh[tid] = c;
    __syncthreads();
    for (int s = 128; s > 0; s >>= 1) {
      if (tid < s) dsh[tid] += dsh[tid + s];
      __syncthreads();
    }
    if (tid == 0) atomicExch(&detcnt[blockIdx.x], (int)dsh[0]);
  }
  if (tid == 0) {
    __threadfence();
    u32 old = atomicAdd(&ctl->done, 1u);
    lastflag = (old == (u32)(nblocks - 1));
  }
  __syncthreads();
  if (!lastflag) return;
  if (tid < 64) {   // wave 0 computes norm + dtype flag
    int dc = atomicAdd(&detcnt[tid], 0);
    for (int off = 32; off; off >>= 1) dc += __shfl_down(dc, off);
    dc = __shfl(dc, 0);
    bool f32 = (dc >= 16);
    float v0 = loadF(pw, tid, f32);
    float v1 = loadF(pw, 64 + tid, f32);
    float s = v0 * v0 + v1 * v1;
    for (int off = 32; off; off >>= 1) s += __shfl_down(s, off);
    if (tid == 0) {
      ctl->inv_norm = 1.0f / sqrtf(s);
      ctl->isfp32 = f32 ? 1u : 0u;
      ctl->done = 0u;
    }
  }
}

// x -> bf16 (copy if already bf16)
__global__ void cvt_kernel(const void* __restrict__ x, u32* __restrict__ xb, const Ctl* __restrict__ ctl) {
  const bool f32 = ctl->isfp32 != 0;
  int p = blockIdx.x * 256 + threadIdx.x;   // pair index
  if (p >= N_NODES * 32) return;
  if (f32) {
    float2 v = ((const float2*)x)[p];
    xb[p] = ((u32)(u16)f2bf_bits(v.x)) | (((u32)(u16)f2bf_bits(v.y)) << 16);
  } else {
    xb[p] = ((const u32*)x)[p];
  }
}

// ------------- CSR1 via bucket sort (proven R8) -------------

__global__ void bucket_scatter_kernel(const int* __restrict__ src, const int* __restrict__ dst,
                                      int* __restrict__ bucket_cur, u32* __restrict__ bucketbuf)
{
  __shared__ u32 hist[BKT];
  __shared__ u32 base[BKT];
  const int tid = threadIdx.x;
  const int e0 = blockIdx.x * 2048;
  for (int t = tid; t < BKT; t += 256) hist[t] = 0;
  __syncthreads();
  #pragma unroll
  for (int j = 0; j < 8; ++j) {
    int e = e0 + j * 256 + tid;
    if (e < N_EDGES) atomicAdd(&hist[dst[e] >> 8], 1u);
  }
  __syncthreads();
  for (int t = tid; t < BKT; t += 256) {
    u32 c = hist[t];
    base[t] = c ? (u32)atomicAdd(&bucket_cur[t], (int)c) : 0u;
    hist[t] = 0;
  }
  __syncthreads();
  #pragma unroll
  for (int j = 0; j < 8; ++j) {
    int e = e0 + j * 256 + tid;
    if (e < N_EDGES) {
      int d = dst[e];
      int b = d >> 8;
      u32 pos = base[b] + atomicAdd(&hist[b], 1u);
      bucketbuf[pos] = ((u32)src[e] << 8) | (u32)(d & 255);
    }
  }
}

// per-block redundant scan of bucket sizes, then count/scan/fill window in LDS
__global__ void csr_from_buckets_kernel(const u32* __restrict__ bucketbuf, const int* __restrict__ bucket_cur,
                                        int* __restrict__ rowstart, float* __restrict__ dis,
                                        int* __restrict__ csr)
{
  __shared__ int sc[256];
  __shared__ u32 cnt[256];
  __shared__ u32 loc[256];
  __shared__ u32 cur[256];
  const int b = blockIdx.x;
  const int tid = threadIdx.x;
  int v = (tid < BKT) ? (bucket_cur[tid] - tid * BCAP) : 0;
  sc[tid] = v;
  __syncthreads();
  for (int off = 1; off < 256; off <<= 1) {
    int t = (tid >= off) ? sc[tid - off] : 0;
    __syncthreads();
    sc[tid] += t;
    __syncthreads();
  }
  const int off0 = (b == 0) ? 0 : sc[b - 1];
  if (b == 0 && tid == 0) rowstart[N_NODES] = sc[BKT - 1];
  const int bc = bucket_cur[b] - b * BCAP;
  const u32* buf = bucketbuf + (size_t)b * BCAP;
  cnt[tid] = 0;
  __syncthreads();
  for (int i = tid; i < bc; i += 256) atomicAdd(&cnt[buf[i] & 255u], 1u);
  __syncthreads();
  u32 c = cnt[tid];
  loc[tid] = c;
  __syncthreads();
  for (int off = 1; off < 256; off <<= 1) {
    u32 t = (tid >= off) ? loc[tid - off] : 0;
    __syncthreads();
    loc[tid] += t;
    __syncthreads();
  }
  int node = b * 256 + tid;
  u32 excl = loc[tid] - c;
  if (node < N_NODES) {
    rowstart[node] = off0 + (int)excl;
    dis[node] = rsqrtf(1.0f + (float)c);
  }
  cur[tid] = off0 + excl;
  __syncthreads();
  for (int i = tid; i < bc; i += 256) {
    u32 p = buf[i];
    u32 pos = atomicAdd(&cur[p & 255u], 1u);
    csr[pos] = (int)(p >> 8);
  }
}

// ---------------- graph2: fused reduce+scan (last-block), then scanout ----------------

__global__ void reduce_scan_kernel(const int* __restrict__ cnt, int* __restrict__ bsum,
                                   int* __restrict__ boff, int n, int* __restrict__ rowstart_n,
                                   Ctl* ctl)
{
  __shared__ int sh[256];
  __shared__ int lastflag;
  const int tid = threadIdx.x;
  int i = blockIdx.x * 256 + tid;
  sh[tid] = (i < n) ? cnt[i] : 0;
  __syncthreads();
  for (int s = 128; s > 0; s >>= 1) {
    if (tid < s) sh[tid] += sh[tid + s];
    __syncthreads();
  }
  if (tid == 0) {
    atomicExch(&bsum[blockIdx.x], sh[0]);
    __threadfence();
    u32 old = atomicAdd(&ctl->done, 1u);
    lastflag = (old == (u32)(gridDim.x - 1));
  }
  __syncthreads();
  if (!lastflag) return;
  int nb = gridDim.x;
  int v = (tid < nb) ? atomicAdd(&bsum[tid], 0) : 0;
  sh[tid] = v;
  __syncthreads();
  for (int off = 1; off < 256; off <<= 1) {
    int t = (tid >= off) ? sh[tid - off] : 0;
    __syncthreads();
    sh[tid] += t;
    __syncthreads();
  }
  if (tid < nb) boff[tid] = sh[tid] - v;
  if (tid == 255) *rowstart_n = sh[255];
  if (tid == 0) ctl->done = 0u;
}

__global__ void block_scanout_kernel(const int* __restrict__ cnt, const int* __restrict__ boff,
                                     int* __restrict__ rowstart, float* __restrict__ dis, int n) {
  __shared__ int sh[256];
  int tid = threadIdx.x;
  int i = blockIdx.x * 256 + tid;
  int c = (i < n) ? cnt[i] : 0;
  sh[tid] = c;
  __syncthreads();
  for (int off = 1; off < 256; off <<= 1) {
    int t = (tid >= off) ? sh[tid - off] : 0;
    __syncthreads();
    sh[tid] += t;
    __syncthreads();
  }
  if (i < n) {
    rowstart[i] = boff[blockIdx.x] + sh[tid] - c;
    dis[i] = rsqrtf(1.0f + (float)c);
  }
}

// ------- CSR2 from CSR1: filter-compact kept rows (proven R8) -------

__global__ void cnt2_kernel(const int* __restrict__ kept, const int* __restrict__ rowstart1,
                            const int* __restrict__ csr1, const int* __restrict__ new_idx,
                            int* __restrict__ cnt2)
{
  int gid = blockIdx.x * 256 + threadIdx.x;
  int kp = gid >> 4;
  int l16 = gid & 15;
  if (kp >= K_KEEP) return;
  int o = kept[kp];
  int i0 = rowstart1[o], i1 = rowstart1[o + 1];
  int c = 0;
  for (int i = i0 + l16; i < i1; i += 16) c += (new_idx[csr1[i]] >= 0);
  c += __shfl_down(c, 8, 16);
  c += __shfl_down(c, 4, 16);
  c += __shfl_down(c, 2, 16);
  c += __shfl_down(c, 1, 16);
  if (l16 == 0) cnt2[kp] = c;
}

__global__ void fill2_kernel(const int* __restrict__ kept, const int* __restrict__ rowstart1,
                             const int* __restrict__ csr1, const int* __restrict__ new_idx,
                             const int* __restrict__ rowstart2, int* __restrict__ csr2)
{
  int gid = blockIdx.x * 256 + threadIdx.x;
  int kp = gid >> 4;
  int l16 = gid & 15;
  if (kp >= K_KEEP) return;
  int o = kept[kp];
  int i0 = rowstart1[o], i1 = rowstart1[o + 1];
  int base = rowstart2[kp];
  int sub = (threadIdx.x & 63) >> 4;
  for (int ib = i0; ib < i1; ib += 16) {
    int i = ib + l16;
    int ns = -1;
    if (i < i1) ns = new_idx[csr1[i]];
    u64 bal = __ballot(ns >= 0);
    u32 m = (u32)((bal >> (sub * 16)) & 0xFFFFull);
    if (ns >= 0) {
      int rank = __popc(m & ((1u << l16) - 1u));
      csr2[base + rank] = ns;
    }
    base += __popc(m);
  }
}

// ------------- conv1 gather on bf16 input features; ILP-8 -------------

__global__ void agg_gather64_in_kernel(const bf16* __restrict__ xb, const int* __restrict__ rowstart,
                                       const int* __restrict__ csr, const float* __restrict__ dis,
                                       bf16* __restrict__ G, int M)
{
  int gid = blockIdx.x * 256 + threadIdx.x;
  int d = gid >> 6;
  int lane = gid & 63;
  if (d >= M) return;
  float dd = dis[d];
  float a = dd * dd * bf2f(xb[(size_t)d * 64 + lane]);
  int i = rowstart[d], i1 = rowstart[d + 1];
  for (; i + 8 <= i1; i += 8) {
    int s[8];
    #pragma unroll
    for (int j = 0; j < 8; ++j) s[j] = csr[i + j];
    float w[8];
    #pragma unroll
    for (int j = 0; j < 8; ++j) w[j] = dd * dis[s[j]];
    float v[8];
    #pragma unroll
    for (int j = 0; j < 8; ++j) v[j] = bf2f(xb[(size_t)s[j] * 64 + lane]);
    #pragma unroll
    for (int j = 0; j < 8; ++j) a += w[j] * v[j];
  }
  for (; i < i1; ++i) {
    int s = csr[i];
    a += dd * dis[s] * bf2f(xb[(size_t)s * 64 + lane]);
  }
  G[(size_t)d * 64 + lane] = __float2bfloat16(a);
}

// ---------------- MFMA GEMMs (16x16x32 bf16, fp32 acc; proven R9) ----------------

// conv1: Y[N,128] = G[N,64] @ W1 + b1, fused pooling score/keys
__global__ void gemm_in_kernel(const bf16* __restrict__ G, const void* __restrict__ W,
                               const void* __restrict__ b, const void* __restrict__ pw,
                               bf16* __restrict__ Y, const Ctl* __restrict__ ctl,
                               float* __restrict__ score, u64* __restrict__ keys)
{
  __shared__ short Xs[64 * 72];
  __shared__ short Wt[128 * 72];
  __shared__ float bs[128];
  __shared__ float ps[128];
  const bool f32 = ctl->isfp32 != 0;
  const int tid = threadIdx.x;
  const int row0 = blockIdx.x * 64;

  for (int i = tid; i < 64 * 128; i += 256) {
    int k = i >> 7, n = i & 127;
    Wt[n * 72 + k] = f32 ? f2bf_bits(((const float*)W)[i]) : ((const short*)W)[i];
  }
  const u32* G2 = (const u32*)G;
  for (int p = tid; p < 64 * 32; p += 256) {
    int r = p >> 5, kp = p & 31;
    int gr = row0 + r;
    u32 v = (gr < N_NODES) ? G2[(size_t)gr * 32 + kp] : 0u;
    *(u32*)&Xs[r * 72 + 2 * kp] = v;
  }
  for (int i = tid; i < 128; i += 256) { bs[i] = loadF(b, i, f32); ps[i] = loadF(pw, i, f32); }
  __syncthreads();

  const int lane = tid & 63;
  const int w = tid >> 6;
  const int l16 = lane & 15;
  const int quad = lane >> 4;
  f32x4 acc[8];
  #pragma unroll
  for (int ct = 0; ct < 8; ++ct) acc[ct] = (f32x4){0.f, 0.f, 0.f, 0.f};
  const int arow = w * 16 + l16;
  #pragma unroll
  for (int kc = 0; kc < 2; ++kc) {
    short8 a = *(short8*)&Xs[arow * 72 + kc * 32 + quad * 8];
    #pragma unroll
    for (int ct = 0; ct < 8; ++ct) {
      short8 bb = *(short8*)&Wt[(ct * 16 + l16) * 72 + kc * 32 + quad * 8];
      acc[ct] = __builtin_amdgcn_mfma_f32_16x16x32_bf16(a, bb, acc[ct], 0, 0, 0);
    }
  }
  float inv_norm = ctl->inv_norm;
  #pragma unroll
  for (int r = 0; r < 4; ++r) {
    int gr = row0 + w * 16 + quad * 4 + r;
    float p = 0.f;
    #pragma unroll
    for (int ct = 0; ct < 8; ++ct) {
      int col = ct * 16 + l16;
      float h = acc[ct][r] + bs[col];
      if (gr < N_NODES) Y[(size_t)gr * 128 + col] = __float2bfloat16(h);
      p += fmaxf(h, 0.f) * ps[col];
    }
    p += __shfl_down(p, 8, 16);
    p += __shfl_down(p, 4, 16);
    p += __shfl_down(p, 2, 16);
    p += __shfl_down(p, 1, 16);
    if (l16 == 0 && gr < N_NODES) {
      float sc = tanhf(p * inv_norm);
      score[gr] = sc;
      u32 u = __float_as_uint(sc);
      u = (u & 0x80000000u) ? ~u : (u | 0x80000000u);
      keys[gr] = (((u64)u) << 16) | (u64)(0xFFFFu - (u32)gr);
    }
  }
}

// conv2 fused: Y[K,64] = (relu(h1[kept[r]])*score[kept[r]]) @ W2
__global__ void gemm_hp_128_64_kernel(const bf16* __restrict__ X, const int* __restrict__ kept,
                                      const float* __restrict__ score, const void* __restrict__ W,
                                      bf16* __restrict__ Y, const Ctl* __restrict__ ctl, int M)
{
  __shared__ short Xs[64 * 136];
  __shared__ short Wt[64 * 136];
  const bool f32 = ctl->isfp32 != 0;
  const int tid = threadIdx.x;
  const int row0 = blockIdx.x * 64;

  for (int i = tid; i < 128 * 64; i += 256) {
    int k = i >> 6, n = i & 63;
    Wt[n * 136 + k] = f32 ? f2bf_bits(((const float*)W)[i]) : ((const short*)W)[i];
  }
  const u32* X2 = (const u32*)X;
  for (int p = tid; p < 64 * 64; p += 256) {
    int r = p >> 6, kp = p & 63;
    int o = kept[row0 + r];
    float s = score[o];
    u32 v = X2[(size_t)o * 64 + kp];
    bf16x2 h = *(bf16x2*)&v;
    float vx = fmaxf(bf2f(h.x), 0.f) * s;
    float vy = fmaxf(bf2f(h.y), 0.f) * s;
    Xs[r * 136 + 2 * kp]     = f2bf_bits(vx);
    Xs[r * 136 + 2 * kp + 1] = f2bf_bits(vy);
  }
  __syncthreads();

  const int lane = tid & 63;
  const int w = tid >> 6;
  const int l16 = lane & 15;
  const int quad = lane >> 4;
  f32x4 acc[4];
  #pragma unroll
  for (int ct = 0; ct < 4; ++ct) acc[ct] = (f32x4){0.f, 0.f, 0.f, 0.f};
  const int arow = w * 16 + l16;
  #pragma unroll
  for (int kc = 0; kc < 4; ++kc) {
    short8 a = *(short8*)&Xs[arow * 136 + kc * 32 + quad * 8];
    #pragma unroll
    for (int ct = 0; ct < 4; ++ct) {
      short8 bb = *(short8*)&Wt[(ct * 16 + l16) * 136 + kc * 32 + quad * 8];
      acc[ct] = __builtin_amdgcn_mfma_f32_16x16x32_bf16(a, bb, acc[ct], 0, 0, 0);
    }
  }
  #pragma unroll
  for (int ct = 0; ct < 4; ++ct)
    #pragma unroll
    for (int r = 0; r < 4; ++r) {
      int gr = row0 + w * 16 + quad * 4 + r;
      Y[(size_t)gr * 64 + ct * 16 + l16] = __float2bfloat16(acc[ct][r]);
    }
}

// conv4: Y[M,64] = relu(X[M,128]) @ W[128,64]
__global__ void gemm_128_64_kernel(const bf16* __restrict__ X, const void* __restrict__ W,
                                   bf16* __restrict__ Y, const Ctl* __restrict__ ctl,
                                   int M, int relu_x)
{
  __shared__ short Xs[64 * 136];
  __shared__ short Wt[64 * 136];
  const bool f32 = ctl->isfp32 != 0;
  const int tid = threadIdx.x;
  const int row0 = blockIdx.x * 64;

  for (int i = tid; i < 128 * 64; i += 256) {
    int k = i >> 6, n = i & 63;
    Wt[n * 136 + k] = f32 ? f2bf_bits(((const float*)W)[i]) : ((const short*)W)[i];
  }
  const u32* X2 = (const u32*)X;
  for (int p = tid; p < 64 * 64; p += 256) {
    int r = p >> 6, kp = p & 63;
    u32 v = X2[(size_t)(row0 + r) * 64 + kp];
    if (relu_x) {
      if (v & 0x8000u) v &= 0xFFFF0000u;
      if (v & 0x80000000u) v &= 0x0000FFFFu;
    }
    *(u32*)&Xs[r * 136 + 2 * kp] = v;
  }
  __syncthreads();

  const int lane = tid & 63;
  const int w = tid >> 6;
  const int l16 = lane & 15;
  const int quad = lane >> 4;
  f32x4 acc[4];
  #pragma unroll
  for (int ct = 0; ct < 4; ++ct) acc[ct] = (f32x4){0.f, 0.f, 0.f, 0.f};
  const int arow = w * 16 + l16;
  #pragma unroll
  for (int kc = 0; kc < 4; ++kc) {
    short8 a = *(short8*)&Xs[arow * 136 + kc * 32 + quad * 8];
    #pragma unroll
    for (int ct = 0; ct < 4; ++ct) {
      short8 bb = *(short8*)&Wt[(ct * 16 + l16) * 136 + kc * 32 + quad * 8];
      acc[ct] = __builtin_amdgcn_mfma_f32_16x16x32_bf16(a, bb, acc[ct], 0, 0, 0);
    }
  }
  #pragma unroll
  for (int ct = 0; ct < 4; ++ct)
    #pragma unroll
    for (int r = 0; r < 4; ++r) {
      int gr = row0 + w * 16 + quad * 4 + r;
      Y[(size_t)gr * 64 + ct * 16 + l16] = __float2bfloat16(acc[ct][r]);
    }
}

// conv3: Y[M,128] = X[M,64] @ W[64,128] + b
__global__ void gemm_64_128_kernel(const bf16* __restrict__ X, const void* __restrict__ W,
                                   const void* __restrict__ b, bf16* __restrict__ Y,
                                   const Ctl* __restrict__ ctl, int M)
{
  __shared__ short Xs[64 * 72];
  __shared__ short Wt[128 * 72];
  __shared__ float bs[128];
  const bool f32 = ctl->isfp32 != 0;
  const int tid = threadIdx.x;
  const int row0 = blockIdx.x * 64;

  for (int i = tid; i < 64 * 128; i += 256) {
    int k = i >> 7, n = i & 127;
    Wt[n * 72 + k] = f32 ? f2bf_bits(((const float*)W)[i]) : ((const short*)W)[i];
  }
  const u32* X2 = (const u32*)X;
  for (int p = tid; p < 64 * 32; p += 256) {
    int r = p >> 5, kp = p & 31;
    *(u32*)&Xs[r * 72 + 2 * kp] = X2[(size_t)(row0 + r) * 32 + kp];
  }
  for (int i = tid; i < 128; i += 256) bs[i] = loadF(b, i, f32);
  __syncthreads();

  const int lane = tid & 63;
  const int w = tid >> 6;
  const int l16 = lane & 15;
  const int quad = lane >> 4;
  f32x4 acc[8];
  #pragma unroll
  for (int ct = 0; ct < 8; ++ct) acc[ct] = (f32x4){0.f, 0.f, 0.f, 0.f};
  const int arow = w * 16 + l16;
  #pragma unroll
  for (int kc = 0; kc < 2; ++kc) {
    short8 a = *(short8*)&Xs[arow * 72 + kc * 32 + quad * 8];
    #pragma unroll
    for (int ct = 0; ct < 8; ++ct) {
      short8 bb = *(short8*)&Wt[(ct * 16 + l16) * 72 + kc * 32 + quad * 8];
      acc[ct] = __builtin_amdgcn_mfma_f32_16x16x32_bf16(a, bb, acc[ct], 0, 0, 0);
    }
  }
  #pragma unroll
  for (int ct = 0; ct < 8; ++ct)
    #pragma unroll
    for (int r = 0; r < 4; ++r) {
      int gr = row0 + w * 16 + quad * 4 + r;
      int col = ct * 16 + l16;
      Y[(size_t)gr * 128 + col] = __float2bfloat16(acc[ct][r] + bs[col]);
    }
}

// --------- gather on bf16 rows (64 ch), optional relu/bias; ILP-8 ---------

__global__ void agg_gather64_kernel(const bf16* __restrict__ hW, const int* __restrict__ rowstart,
                                    const int* __restrict__ csr, const float* __restrict__ dis,
                                    const void* __restrict__ b, const Ctl* __restrict__ ctl,
                                    bf16* __restrict__ agg, int M, int relusrc, int addbias)
{
  const bool f32 = ctl->isfp32 != 0;
  int gid = blockIdx.x * 256 + threadIdx.x;
  int d = gid >> 6;
  int lane = gid & 63;
  if (d >= M) return;
  float dd = dis[d];
  float v = bf2f(hW[(size_t)d * 64 + lane]);
  if (relusrc) v = fmaxf(v, 0.f);
  float a = v * dd * dd + (addbias ? loadF(b, lane, f32) : 0.f);
  int i = rowstart[d], i1 = rowstart[d + 1];
  for (; i + 8 <= i1; i += 8) {
    int s[8];
    #pragma unroll
    for (int j = 0; j < 8; ++j) s[j] = csr[i + j];
    float w[8];
    #pragma unroll
    for (int j = 0; j < 8; ++j) w[j] = dd * dis[s[j]];
    float vv[8];
    #pragma unroll
    for (int j = 0; j < 8; ++j) vv[j] = bf2f(hW[(size_t)s[j] * 64 + lane]);
    if (relusrc) {
      #pragma unroll
      for (int j = 0; j < 8; ++j) vv[j] = fmaxf(vv[j], 0.f);
    }
    #pragma unroll
    for (int j = 0; j < 8; ++j) a += w[j] * vv[j];
  }
  for (; i < i1; ++i) {
    int s = csr[i];
    float vv = bf2f(hW[(size_t)s * 64 + lane]);
    if (relusrc) vv = fmaxf(vv, 0.f);
    a += dd * dis[s] * vv;
  }
  agg[(size_t)d * 64 + lane] = __float2bfloat16(a);
}

// conv4: gather + bias + per-block mean-pool partial (plain stores); ILP-8
__global__ void agg_gather64_final_kernel(const bf16* __restrict__ hW, const int* __restrict__ rowstart,
                                          const int* __restrict__ csr, const float* __restrict__ dis,
                                          const void* __restrict__ b, const Ctl* __restrict__ ctl,
                                          float* __restrict__ partial, int M)
{
  __shared__ float cs[64];
  const bool f32 = ctl->isfp32 != 0;
  int tid = threadIdx.x;
  if (tid < 64) cs[tid] = 0.f;
  __syncthreads();
  int gid = blockIdx.x * 256 + tid;
  int d = gid >> 6;
  int lane = gid & 63;
  if (d < M) {
    float dd = dis[d];
    float a = bf2f(hW[(size_t)d * 64 + lane]) * (dd * dd) + loadF(b, lane, f32);
    int i = rowstart[d], i1 = rowstart[d + 1];
    for (; i + 8 <= i1; i += 8) {
      int s[8];
      #pragma unroll
      for (int j = 0; j < 8; ++j) s[j] = csr[i + j];
      float w[8];
      #pragma unroll
      for (int j = 0; j < 8; ++j) w[j] = dd * dis[s[j]];
      float vv[8];
      #pragma unroll
      for (int j = 0; j < 8; ++j) vv[j] = bf2f(hW[(size_t)s[j] * 64 + lane]);
      #pragma unroll
      for (int j = 0; j < 8; ++j) a += w[j] * vv[j];
    }
    for (; i < i1; ++i) {
      int s = csr[i];
      a += dd * dis[s] * bf2f(hW[(size_t)s * 64 + lane]);
    }
    atomicAdd(&cs[lane], a);
  }
  __syncthreads();
  if (tid < 64) partial[(size_t)tid * gridDim.x + blockIdx.x] = cs[tid];
}

__global__ void reduce_out_kernel(const float* __restrict__ partial, const Ctl* __restrict__ ctl,
                                  void* __restrict__ out, int nblk)
{
  __shared__ float sh[256];
  int c = blockIdx.x;
  float s = 0.f;
  for (int j = threadIdx.x; j < nblk; j += 256) s += partial[(size_t)c * nblk + j];
  sh[threadIdx.x] = s;
  __syncthreads();
  for (int st = 128; st > 0; st >>= 1) {
    if (threadIdx.x < st) sh[threadIdx.x] += sh[threadIdx.x + st];
    __syncthreads();
  }
  if (threadIdx.x == 0) {
    float val = sh[0] / (float)K_KEEP;
    if (ctl->isfp32) ((float*)out)[c] = val;
    else             ((bf16*)out)[c] = __float2bfloat16(val);
  }
}

// ---------------- TopK select: separate histpick passes (R10-proven) ----------------
// R11 lesson: a fused spin-barrier version costs ~20us/barrier-round across
// 196 blocks (8 non-coherent XCD L2s hammering one line) — worse than
// separate kernel launches. Keep multi-kernel.

__global__ void histpick_kernel(const u64* __restrict__ keys, Ctl* ctl, int shift, int nblocks) {
  __shared__ u32 lh[256];
  __shared__ int lastflag;
  const int tid = threadIdx.x;
  lh[tid] = 0;
  __syncthreads();
  u64 prefix = ctl->prefix;
  int i = blockIdx.x * 256 + tid;
  if (i < N_NODES) {
    u64 key = keys[i];
    if ((key >> (shift + 8)) == (prefix >> (shift + 8)))
      atomicAdd(&lh[(u32)((key >> shift) & 0xFF)], 1u);
  }
  __syncthreads();
  u32 c = lh[tid];
  if (c) atomicAdd(&ctl->hist[tid], c);
  __syncthreads();
  if (tid == 0) {
    __threadfence();
    u32 old = atomicAdd(&ctl->done, 1u);
    lastflag = (old == (u32)(nblocks - 1));
  }
  __syncthreads();
  if (!lastflag) return;
  lh[tid] = atomicExch(&ctl->hist[tid], 0u);
  __syncthreads();
  if (tid == 0) {
    u32 kr = ctl->kremain;
    u32 cum = 0;
    int sel = 0;
    for (int v = 255; v >= 0; --v) {
      u32 cc = lh[v];
      if (cum + cc >= kr) { sel = v; break; }
      cum += cc;
    }
    ctl->prefix = prefix | (((u64)sel) << shift);
    ctl->kremain = kr - cum;
    ctl->done = 0u;
  }
}

// block-aggregated mark: 1 global atomic per block
__global__ void mark_kernel(const u64* __restrict__ keys, Ctl* ctl,
                            int* __restrict__ new_idx, int* __restrict__ kept)
{
  __shared__ u32 cnts[4];
  __shared__ u32 wbase[4];
  const int tid = threadIdx.x;
  int i = blockIdx.x * 256 + tid;
  bool sel = false;
  if (i < N_NODES) sel = (keys[i] >= ctl->prefix);
  u64 bal = __ballot(sel);
  int lane = tid & 63;
  int w = tid >> 6;
  if (lane == 0) cnts[w] = (u32)__popcll(bal);
  __syncthreads();
  if (tid == 0) {
    u32 tot = cnts[0] + cnts[1] + cnts[2] + cnts[3];
    u32 base = atomicAdd(&ctl->cnt, tot);
    wbase[0] = base;
    wbase[1] = base + cnts[0];
    wbase[2] = base + cnts[0] + cnts[1];
    wbase[3] = base + cnts[0] + cnts[1] + cnts[2];
  }
  __syncthreads();
  if (i < N_NODES) {
    if (sel) {
      int pos = (int)(wbase[w] + (u32)__popcll(bal & ((1ull << lane) - 1ull)));
      new_idx[i] = pos;
      kept[pos] = i;
    } else {
      new_idx[i] = -1;
    }
  }
}

// ---------------- launch ----------------

extern "C" void kernel_launch(void* const* d_in, const int* in_sizes, int n_in,
                              void* d_out, int out_size, void* d_ws, size_t ws_size,
                              hipStream_t stream)
{
  const void* x  = d_in[0];
  const int*  ei = (const int*)d_in[1];
  const void* W1 = d_in[3];
  const void* b1 = d_in[4];
  const void* pw = d_in[5];
  const void* W2 = d_in[6];
  const void* b2 = d_in[7];
  const void* W3 = d_in[8];
  const void* b3 = d_in[9];
  const void* W4 = d_in[10];
  const void* b4 = d_in[11];

  const int* src = ei;
  const int* dst = ei + N_EDGES;

  float* F = (float*)d_ws;
  bf16*  A16       = (bf16*)F;               // N x 128 bf16
  bf16*  B16       = (bf16*)(F + 3200000);   // N x 128 bf16
  bf16*  C16       = (bf16*)(F + 6400000);   // K x 128 bf16 (conv1 G / h2)
  float* dis1      = F + 9000000;            // 50000
  float* dis2      = F + 9050000;            // 40000
  float* score     = F + 9100000;            // 50000
  u64*   keys      = (u64*)(F + 9150000);    // 50000 u64
  int*   new_idx   = (int*)(F + 9250000);    // 50000
  int*   kept      = (int*)(F + 9300000);    // 40000
  int*   cnt2      = (int*)(F + 9340000);    // 40000
  int*   rowstart1 = (int*)(F + 9380000);    // 50001
  int*   rowstart2 = (int*)(F + 9430004);    // 40001
  int*   csr1      = (int*)(F + 9470008);    // 800000
  int*   csr2      = (int*)(F + 10270008);   // 800000
  Ctl*   ctl       = (Ctl*)(F + 11070008);   // ~1.1 KB
  int*   bsum      = (int*)(F + 11070500);   // 256
  int*   boff      = (int*)(F + 11070756);   // 256
  int*   detcnt    = (int*)(F + 11071012);   // 64
  int*   bucket_cur= (int*)(F + 11071076);   // 196
  u32*   bucketbuf = (u32*)(F + 11071332);   // 196*6144
  float* partial   = F + 12275556;           // 64 x 10000
  bf16*  xb16      = (bf16*)(F + 12915556);  // N x 64 bf16

  const int NB1 = (N_NODES + 255) / 256;     // 196
  const int NB2 = (K_KEEP + 255) / 256;      // 157
  const int EB2 = (N_EDGES + 2047) / 2048;   // 391
  const int SGB = (K_KEEP * 16 + 255) / 256; // 2500
  const int GFB = K_KEEP / 4;                // 10000

  hipMemsetAsync(ctl, 0, sizeof(Ctl), stream);
  init_norm_kernel<<<NB1, 256, 0, stream>>>((const unsigned short*)x, bucket_cur, detcnt, pw, ctl, NB1);
  cvt_kernel<<<(N_NODES * 32 + 255) / 256, 256, 0, stream>>>(x, (u32*)xb16, ctl);

  // CSR graph 1 via bucket sort
  bucket_scatter_kernel<<<EB2, 256, 0, stream>>>(src, dst, bucket_cur, bucketbuf);
  csr_from_buckets_kernel<<<BKT, 256, 0, stream>>>(bucketbuf, bucket_cur, rowstart1, dis1, csr1);

  // conv1 (gather-first): G = A_norm . x ; h1 = G @ W1 + b1 (+fused score)
  agg_gather64_in_kernel<<<(N_NODES + 3) / 4, 256, 0, stream>>>(xb16, rowstart1, csr1, dis1, C16, N_NODES);
  gemm_in_kernel<<<(N_NODES + 63) / 64, 256, 0, stream>>>(C16, W1, b1, pw, B16, ctl, score, keys);

  // top-K select (6 x 8-bit radix over 48-bit keys) + block-aggregated mark
  for (int p = 0; p < 6; ++p)
    histpick_kernel<<<NB1, 256, 0, stream>>>(keys, ctl, 40 - 8 * p, NB1);
  mark_kernel<<<NB1, 256, 0, stream>>>(keys, ctl, new_idx, kept);

  // CSR graph 2: filter-compact kept rows of csr1
  cnt2_kernel<<<SGB, 256, 0, stream>>>(kept, rowstart1, csr1, new_idx, cnt2);
  reduce_scan_kernel<<<NB2, 256, 0, stream>>>(cnt2, bsum, boff, K_KEEP, &rowstart2[K_KEEP], ctl);
  block_scanout_kernel<<<NB2, 256, 0, stream>>>(cnt2, boff, rowstart2, dis2, K_KEEP);
  fill2_kernel<<<SGB, 256, 0, stream>>>(kept, rowstart1, csr1, new_idx, rowstart2, csr2);

  // conv2 (hp fused into gemm): A = (relu(h1[kept])*score) @ W2 ; h2 = gather(A) + b2
  gemm_hp_128_64_kernel<<<K_KEEP / 64, 256, 0, stream>>>(B16, kept, score, W2, A16, ctl, K_KEEP);
  agg_gather64_kernel<<<K_KEEP / 4, 256, 0, stream>>>(A16, rowstart2, csr2, dis2, b2, ctl, C16, K_KEEP, 0, 1);

  // conv3: gather-first: G = gather(relu(h2)) ; h3 = G @ W3 + b3
  agg_gather64_kernel<<<K_KEEP / 4, 256, 0, stream>>>(C16, rowstart2, csr2, dis2, b3, ctl, A16, K_KEEP, 1, 0);
  gemm_64_128_kernel<<<K_KEEP / 64, 256, 0, stream>>>(A16, W3, b3, B16, ctl, K_KEEP);

  // conv4: gemm-first: A = relu(h3) @ W4 ; partials = gather(A) + b4
  gemm_128_64_kernel<<<K_KEEP / 64, 256, 0, stream>>>(B16, W4, A16, ctl, K_KEEP, 1);
  agg_gather64_final_kernel<<<GFB, 256, 0, stream>>>(A16, rowstart2, csr2, dis2, b4, ctl, partial, K_KEEP);

  reduce_out_kernel<<<64, 256, 0, stream>>>(partial, ctl, d_out, GFB);
}

// Round 13
// 414.501 us; speedup vs baseline: 1.1266x; 1.0504x over previous
//
#include <hip/hip_runtime.h>
#include <hip/hip_bf16.h>
#include <stdint.h>

#define N_NODES 50000
#define N_EDGES 800000
#define K_KEEP  40000
#define BKT     196        // ceil(N_NODES/256) dst-range buckets
#define BCAP    6144       // per-bucket capacity (mean 4081, +32 sigma)

typedef unsigned long long u64;
typedef unsigned int u32;
typedef unsigned short u16;
typedef __hip_bfloat16 bf16;
typedef __hip_bfloat162 bf16x2;
typedef __attribute__((ext_vector_type(8))) short short8;
typedef __attribute__((ext_vector_type(4))) float f32x4;

struct Ctl {
  u64 prefix;
  u32 kremain;
  u32 cnt;
  float inv_norm;
  u32 isfp32;
  u32 done;
  u32 pad;
  u32 hist[256];
};

__device__ __forceinline__ float bf2f(bf16 v) { return __bfloat162float(v); }
__device__ __forceinline__ float loadF(const void* p, size_t i, bool f32) {
  return f32 ? ((const float*)p)[i] : bf2f(((const bf16*)p)[i]);
}
__device__ __forceinline__ short f2bf_bits(float f) {
  bf16 t = __float2bfloat16(f);
  return *(const short*)&t;
}

// ---------------- init (+parallel dtype detect, proven R5-R8) ----------------

__global__ void init_kernel(const unsigned short* __restrict__ x16,
                            int* __restrict__ bucket_cur, int* __restrict__ detcnt, Ctl* ctl) {
  __shared__ u32 dsh[256];
  int i = blockIdx.x * 256 + threadIdx.x;
  if (i < BKT) bucket_cur[i] = i * BCAP;
  if (blockIdx.x == 0) {
    ctl->hist[threadIdx.x] = 0u;
    if (threadIdx.x == 0) { ctl->prefix = 0ull; ctl->kremain = K_KEEP; ctl->cnt = 0u; ctl->done = 0u; }
  }
  if (blockIdx.x < 64) {
    int base = blockIdx.x * 2048;
    u32 c = 0;
    for (int j = threadIdx.x; j < 2048; j += 256) {
      u32 h = x16[base + j];
      if ((h & 0x7F80u) == 0x7F80u) c++;
    }
    dsh[threadIdx.x] = c;
    __syncthreads();
    for (int s = 128; s > 0; s >>= 1) {
      if (threadIdx.x < s) dsh[threadIdx.x] += dsh[threadIdx.x + s];
      __syncthreads();
    }
    if (threadIdx.x == 0) detcnt[blockIdx.x] = (int)dsh[0];
  }
}

__global__ void norm_kernel(const void* __restrict__ pw, const int* __restrict__ detcnt, Ctl* ctl) {
  int lane = threadIdx.x;   // 64
  int dc = detcnt[lane];
  for (int off = 32; off; off >>= 1) dc += __shfl_down(dc, off);
  dc = __shfl(dc, 0);
  bool f32 = (dc >= 16);
  float v0 = loadF(pw, lane, f32);
  float v1 = loadF(pw, 64 + lane, f32);
  float s = v0 * v0 + v1 * v1;
  for (int off = 32; off; off >>= 1) s += __shfl_down(s, off);
  if (lane == 0) {
    ctl->inv_norm = 1.0f / sqrtf(s);
    ctl->isfp32 = f32 ? 1u : 0u;
  }
}

// ------------- CSR1 via bucket sort (proven R8) -------------

__global__ void bucket_scatter_kernel(const int* __restrict__ src, const int* __restrict__ dst,
                                      int* __restrict__ bucket_cur, u32* __restrict__ bucketbuf)
{
  __shared__ u32 hist[BKT];
  __shared__ u32 base[BKT];
  const int tid = threadIdx.x;
  const int e0 = blockIdx.x * 2048;
  for (int t = tid; t < BKT; t += 256) hist[t] = 0;
  __syncthreads();
  #pragma unroll
  for (int j = 0; j < 8; ++j) {
    int e = e0 + j * 256 + tid;
    if (e < N_EDGES) atomicAdd(&hist[dst[e] >> 8], 1u);
  }
  __syncthreads();
  for (int t = tid; t < BKT; t += 256) {
    u32 c = hist[t];
    base[t] = c ? (u32)atomicAdd(&bucket_cur[t], (int)c) : 0u;
    hist[t] = 0;
  }
  __syncthreads();
  #pragma unroll
  for (int j = 0; j < 8; ++j) {
    int e = e0 + j * 256 + tid;
    if (e < N_EDGES) {
      int d = dst[e];
      int b = d >> 8;
      u32 pos = base[b] + atomicAdd(&hist[b], 1u);
      bucketbuf[pos] = ((u32)src[e] << 8) | (u32)(d & 255);
    }
  }
}

__global__ void scan_buckets_kernel(const int* __restrict__ bucket_cur, int* __restrict__ boff,
                                    int* __restrict__ rowstart_n)
{
  __shared__ int sh[256];
  int tid = threadIdx.x;
  int v = (tid < BKT) ? (bucket_cur[tid] - tid * BCAP) : 0;
  sh[tid] = v;
  __syncthreads();
  for (int off = 1; off < 256; off <<= 1) {
    int t = (tid >= off) ? sh[tid - off] : 0;
    __syncthreads();
    sh[tid] += t;
    __syncthreads();
  }
  if (tid < BKT) boff[tid] = sh[tid] - v;
  if (tid == 255) *rowstart_n = sh[255];
}

__global__ void csr_from_buckets_kernel(const u32* __restrict__ bucketbuf, const int* __restrict__ bucket_cur,
                                        const int* __restrict__ boff, int* __restrict__ rowstart,
                                        float* __restrict__ dis, int* __restrict__ csr)
{
  __shared__ u32 cnt[256];
  __shared__ u32 loc[256];
  __shared__ u32 cur[256];
  const int b = blockIdx.x;
  const int tid = threadIdx.x;
  const int bc = bucket_cur[b] - b * BCAP;
  const u32* buf = bucketbuf + (size_t)b * BCAP;
  const int off0 = boff[b];
  cnt[tid] = 0;
  __syncthreads();
  for (int i = tid; i < bc; i += 256) atomicAdd(&cnt[buf[i] & 255u], 1u);
  __syncthreads();
  u32 c = cnt[tid];
  loc[tid] = c;
  __syncthreads();
  for (int off = 1; off < 256; off <<= 1) {
    u32 t = (tid >= off) ? loc[tid - off] : 0;
    __syncthreads();
    loc[tid] += t;
    __syncthreads();
  }
  int node = b * 256 + tid;
  u32 excl = loc[tid] - c;
  if (node < N_NODES) {
    rowstart[node] = off0 + (int)excl;
    dis[node] = rsqrtf(1.0f + (float)c);
  }
  cur[tid] = off0 + excl;
  __syncthreads();
  for (int i = tid; i < bc; i += 256) {
    u32 p = buf[i];
    u32 pos = atomicAdd(&cur[p & 255u], 1u);
    csr[pos] = (int)(p >> 8);
  }
}

// ---------------- hierarchical scan (graph2 only) ----------------

__global__ void block_reduce_kernel(const int* __restrict__ cnt, int* __restrict__ bsum, int n) {
  __shared__ int sh[256];
  int i = blockIdx.x * 256 + threadIdx.x;
  sh[threadIdx.x] = (i < n) ? cnt[i] : 0;
  __syncthreads();
  for (int s = 128; s > 0; s >>= 1) {
    if (threadIdx.x < s) sh[threadIdx.x] += sh[threadIdx.x + s];
    __syncthreads();
  }
  if (threadIdx.x == 0) bsum[blockIdx.x] = sh[0];
}

__global__ void scan_bsum_kernel(const int* __restrict__ bsum, int* __restrict__ boff,
                                 int nb, int* __restrict__ rowstart_n) {
  __shared__ int sh[256];
  int tid = threadIdx.x;
  int v = (tid < nb) ? bsum[tid] : 0;
  sh[tid] = v;
  __syncthreads();
  for (int off = 1; off < 256; off <<= 1) {
    int t = (tid >= off) ? sh[tid - off] : 0;
    __syncthreads();
    sh[tid] += t;
    __syncthreads();
  }
  if (tid < nb) boff[tid] = sh[tid] - v;
  if (tid == 255) *rowstart_n = sh[255];
}

__global__ void block_scanout_kernel(const int* __restrict__ cnt, const int* __restrict__ boff,
                                     int* __restrict__ rowstart, float* __restrict__ dis, int n) {
  __shared__ int sh[256];
  int tid = threadIdx.x;
  int i = blockIdx.x * 256 + tid;
  int c = (i < n) ? cnt[i] : 0;
  sh[tid] = c;
  __syncthreads();
  for (int off = 1; off < 256; off <<= 1) {
    int t = (tid >= off) ? sh[tid - off] : 0;
    __syncthreads();
    sh[tid] += t;
    __syncthreads();
  }
  if (i < n) {
    rowstart[i] = boff[blockIdx.x] + sh[tid] - c;
    dis[i] = rsqrtf(1.0f + (float)c);
  }
}

// ------- CSR2 from CSR1: filter-compact kept rows (proven R8) -------

__global__ void cnt2_kernel(const int* __restrict__ kept, const int* __restrict__ rowstart1,
                            const int* __restrict__ csr1, const int* __restrict__ new_idx,
                            int* __restrict__ cnt2)
{
  int gid = blockIdx.x * 256 + threadIdx.x;
  int kp = gid >> 4;
  int l16 = gid & 15;
  if (kp >= K_KEEP) return;
  int o = kept[kp];
  int i0 = rowstart1[o], i1 = rowstart1[o + 1];
  int c = 0;
  for (int i = i0 + l16; i < i1; i += 16) c += (new_idx[csr1[i]] >= 0);
  c += __shfl_down(c, 8, 16);
  c += __shfl_down(c, 4, 16);
  c += __shfl_down(c, 2, 16);
  c += __shfl_down(c, 1, 16);
  if (l16 == 0) cnt2[kp] = c;
}

__global__ void fill2_kernel(const int* __restrict__ kept, const int* __restrict__ rowstart1,
                             const int* __restrict__ csr1, const int* __restrict__ new_idx,
                             const int* __restrict__ rowstart2, int* __restrict__ csr2)
{
  int gid = blockIdx.x * 256 + threadIdx.x;
  int kp = gid >> 4;
  int l16 = gid & 15;
  if (kp >= K_KEEP) return;
  int o = kept[kp];
  int i0 = rowstart1[o], i1 = rowstart1[o + 1];
  int base = rowstart2[kp];
  int sub = (threadIdx.x & 63) >> 4;
  for (int ib = i0; ib < i1; ib += 16) {
    int i = ib + l16;
    int ns = -1;
    if (i < i1) ns = new_idx[csr1[i]];
    u64 bal = __ballot(ns >= 0);
    u32 m = (u32)((bal >> (sub * 16)) & 0xFFFFull);
    if (ns >= 0) {
      int rank = __popc(m & ((1u << l16) - 1u));
      csr2[base + rank] = ns;
    }
    base += __popc(m);
  }
}

// ------------- conv1 gather on input features; ILP-4 (proven R7/R8) -------------

__global__ void agg_gather64_in_kernel(const void* __restrict__ xv, const int* __restrict__ rowstart,
                                       const int* __restrict__ csr, const float* __restrict__ dis,
                                       const Ctl* __restrict__ ctl, bf16* __restrict__ G, int M)
{
  const bool f32 = ctl->isfp32 != 0;
  int gid = blockIdx.x * 256 + threadIdx.x;
  int d = gid >> 6;
  int lane = gid & 63;
  if (d >= M) return;
  float dd = dis[d];
  float a = dd * dd * loadF(xv, (size_t)d * 64 + lane, f32);
  int i = rowstart[d], i1 = rowstart[d + 1];
  for (; i + 4 <= i1; i += 4) {
    int s0 = csr[i], s1 = csr[i + 1], s2 = csr[i + 2], s3 = csr[i + 3];
    float w0 = dd * dis[s0], w1 = dd * dis[s1], w2 = dd * dis[s2], w3 = dd * dis[s3];
    float v0 = loadF(xv, (size_t)s0 * 64 + lane, f32);
    float v1 = loadF(xv, (size_t)s1 * 64 + lane, f32);
    float v2 = loadF(xv, (size_t)s2 * 64 + lane, f32);
    float v3 = loadF(xv, (size_t)s3 * 64 + lane, f32);
    a += w0 * v0 + w1 * v1 + w2 * v2 + w3 * v3;
  }
  for (; i < i1; ++i) {
    int s = csr[i];
    a += dd * dis[s] * loadF(xv, (size_t)s * 64 + lane, f32);
  }
  G[(size_t)d * 64 + lane] = __float2bfloat16(a);
}

// ---------------- MFMA GEMMs (16x16x32 bf16, fp32 acc) ----------------

// conv1: Y[N,128] = G[N,64] @ W1 + b1, fused pooling score/keys
__global__ void gemm_in_kernel(const bf16* __restrict__ G, const void* __restrict__ W,
                               const void* __restrict__ b, const void* __restrict__ pw,
                               bf16* __restrict__ Y, const Ctl* __restrict__ ctl,
                               float* __restrict__ score, u64* __restrict__ keys)
{
  __shared__ short Xs[64 * 72];
  __shared__ short Wt[128 * 72];
  __shared__ float bs[128];
  __shared__ float ps[128];
  const bool f32 = ctl->isfp32 != 0;
  const int tid = threadIdx.x;
  const int row0 = blockIdx.x * 64;

  for (int i = tid; i < 64 * 128; i += 256) {
    int k = i >> 7, n = i & 127;
    Wt[n * 72 + k] = f32 ? f2bf_bits(((const float*)W)[i]) : ((const short*)W)[i];
  }
  const u32* G2 = (const u32*)G;
  for (int p = tid; p < 64 * 32; p += 256) {
    int r = p >> 5, kp = p & 31;
    int gr = row0 + r;
    u32 v = (gr < N_NODES) ? G2[(size_t)gr * 32 + kp] : 0u;
    *(u32*)&Xs[r * 72 + 2 * kp] = v;
  }
  for (int i = tid; i < 128; i += 256) { bs[i] = loadF(b, i, f32); ps[i] = loadF(pw, i, f32); }
  __syncthreads();

  const int lane = tid & 63;
  const int w = tid >> 6;
  const int l16 = lane & 15;
  const int quad = lane >> 4;
  f32x4 acc[8];
  #pragma unroll
  for (int ct = 0; ct < 8; ++ct) acc[ct] = (f32x4){0.f, 0.f, 0.f, 0.f};
  const int arow = w * 16 + l16;
  #pragma unroll
  for (int kc = 0; kc < 2; ++kc) {
    short8 a = *(short8*)&Xs[arow * 72 + kc * 32 + quad * 8];
    #pragma unroll
    for (int ct = 0; ct < 8; ++ct) {
      short8 bb = *(short8*)&Wt[(ct * 16 + l16) * 72 + kc * 32 + quad * 8];
      acc[ct] = __builtin_amdgcn_mfma_f32_16x16x32_bf16(a, bb, acc[ct], 0, 0, 0);
    }
  }
  float inv_norm = ctl->inv_norm;
  #pragma unroll
  for (int r = 0; r < 4; ++r) {
    int gr = row0 + w * 16 + quad * 4 + r;
    float p = 0.f;
    #pragma unroll
    for (int ct = 0; ct < 8; ++ct) {
      int col = ct * 16 + l16;
      float h = acc[ct][r] + bs[col];
      if (gr < N_NODES) Y[(size_t)gr * 128 + col] = __float2bfloat16(h);
      p += fmaxf(h, 0.f) * ps[col];
    }
    p += __shfl_down(p, 8, 16);
    p += __shfl_down(p, 4, 16);
    p += __shfl_down(p, 2, 16);
    p += __shfl_down(p, 1, 16);
    if (l16 == 0 && gr < N_NODES) {
      float sc = tanhf(p * inv_norm);
      score[gr] = sc;
      u32 u = __float_as_uint(sc);
      u = (u & 0x80000000u) ? ~u : (u | 0x80000000u);
      keys[gr] = (((u64)u) << 16) | (u64)(0xFFFFu - (u32)gr);
    }
  }
}

// Y[M,64] = (relu?)X[M,128] @ W[128,64]; M multiple of 64
__global__ void gemm_128_64_kernel(const bf16* __restrict__ X, const void* __restrict__ W,
                                   bf16* __restrict__ Y, const Ctl* __restrict__ ctl,
                                   int M, int relu_x)
{
  __shared__ short Xs[64 * 136];
  __shared__ short Wt[64 * 136];
  const bool f32 = ctl->isfp32 != 0;
  const int tid = threadIdx.x;
  const int row0 = blockIdx.x * 64;

  for (int i = tid; i < 128 * 64; i += 256) {
    int k = i >> 6, n = i & 63;
    Wt[n * 136 + k] = f32 ? f2bf_bits(((const float*)W)[i]) : ((const short*)W)[i];
  }
  const u32* X2 = (const u32*)X;
  for (int p = tid; p < 64 * 64; p += 256) {
    int r = p >> 6, kp = p & 63;
    u32 v = X2[(size_t)(row0 + r) * 64 + kp];
    if (relu_x) {
      if (v & 0x8000u) v &= 0xFFFF0000u;
      if (v & 0x80000000u) v &= 0x0000FFFFu;
    }
    *(u32*)&Xs[r * 136 + 2 * kp] = v;
  }
  __syncthreads();

  const int lane = tid & 63;
  const int w = tid >> 6;
  const int l16 = lane & 15;
  const int quad = lane >> 4;
  f32x4 acc[4];
  #pragma unroll
  for (int ct = 0; ct < 4; ++ct) acc[ct] = (f32x4){0.f, 0.f, 0.f, 0.f};
  const int arow = w * 16 + l16;
  #pragma unroll
  for (int kc = 0; kc < 4; ++kc) {
    short8 a = *(short8*)&Xs[arow * 136 + kc * 32 + quad * 8];
    #pragma unroll
    for (int ct = 0; ct < 4; ++ct) {
      short8 bb = *(short8*)&Wt[(ct * 16 + l16) * 136 + kc * 32 + quad * 8];
      acc[ct] = __builtin_amdgcn_mfma_f32_16x16x32_bf16(a, bb, acc[ct], 0, 0, 0);
    }
  }
  #pragma unroll
  for (int ct = 0; ct < 4; ++ct)
    #pragma unroll
    for (int r = 0; r < 4; ++r) {
      int gr = row0 + w * 16 + quad * 4 + r;
      Y[(size_t)gr * 64 + ct * 16 + l16] = __float2bfloat16(acc[ct][r]);
    }
}

// conv3: Y[M,128] = X[M,64] @ W[64,128] + b; M multiple of 64
__global__ void gemm_64_128_kernel(const bf16* __restrict__ X, const void* __restrict__ W,
                                   const void* __restrict__ b, bf16* __restrict__ Y,
                                   const Ctl* __restrict__ ctl, int M)
{
  __shared__ short Xs[64 * 72];
  __shared__ short Wt[128 * 72];
  __shared__ float bs[128];
  const bool f32 = ctl->isfp32 != 0;
  const int tid = threadIdx.x;
  const int row0 = blockIdx.x * 64;

  for (int i = tid; i < 64 * 128; i += 256) {
    int k = i >> 7, n = i & 127;
    Wt[n * 72 + k] = f32 ? f2bf_bits(((const float*)W)[i]) : ((const short*)W)[i];
  }
  const u32* X2 = (const u32*)X;
  for (int p = tid; p < 64 * 32; p += 256) {
    int r = p >> 5, kp = p & 31;
    *(u32*)&Xs[r * 72 + 2 * kp] = X2[(size_t)(row0 + r) * 32 + kp];
  }
  for (int i = tid; i < 128; i += 256) bs[i] = loadF(b, i, f32);
  __syncthreads();

  const int lane = tid & 63;
  const int w = tid >> 6;
  const int l16 = lane & 15;
  const int quad = lane >> 4;
  f32x4 acc[8];
  #pragma unroll
  for (int ct = 0; ct < 8; ++ct) acc[ct] = (f32x4){0.f, 0.f, 0.f, 0.f};
  const int arow = w * 16 + l16;
  #pragma unroll
  for (int kc = 0; kc < 2; ++kc) {
    short8 a = *(short8*)&Xs[arow * 72 + kc * 32 + quad * 8];
    #pragma unroll
    for (int ct = 0; ct < 8; ++ct) {
      short8 bb = *(short8*)&Wt[(ct * 16 + l16) * 72 + kc * 32 + quad * 8];
      acc[ct] = __builtin_amdgcn_mfma_f32_16x16x32_bf16(a, bb, acc[ct], 0, 0, 0);
    }
  }
  #pragma unroll
  for (int ct = 0; ct < 8; ++ct)
    #pragma unroll
    for (int r = 0; r < 4; ++r) {
      int gr = row0 + w * 16 + quad * 4 + r;
      int col = ct * 16 + l16;
      Y[(size_t)gr * 128 + col] = __float2bfloat16(acc[ct][r] + bs[col]);
    }
}

// --------- gather on bf16 rows (64 ch), optional relu/bias; ILP-4 ---------

__global__ void agg_gather64_kernel(const bf16* __restrict__ hW, const int* __restrict__ rowstart,
                                    const int* __restrict__ csr, const float* __restrict__ dis,
                                    const void* __restrict__ b, const Ctl* __restrict__ ctl,
                                    bf16* __restrict__ agg, int M, int relusrc, int addbias)
{
  const bool f32 = ctl->isfp32 != 0;
  int gid = blockIdx.x * 256 + threadIdx.x;
  int d = gid >> 6;
  int lane = gid & 63;
  if (d >= M) return;
  float dd = dis[d];
  float v = bf2f(hW[(size_t)d * 64 + lane]);
  if (relusrc) v = fmaxf(v, 0.f);
  float a = v * dd * dd + (addbias ? loadF(b, lane, f32) : 0.f);
  int i = rowstart[d], i1 = rowstart[d + 1];
  for (; i + 4 <= i1; i += 4) {
    int s0 = csr[i], s1 = csr[i + 1], s2 = csr[i + 2], s3 = csr[i + 3];
    float w0 = dd * dis[s0], w1 = dd * dis[s1], w2 = dd * dis[s2], w3 = dd * dis[s3];
    float v0 = bf2f(hW[(size_t)s0 * 64 + lane]);
    float v1 = bf2f(hW[(size_t)s1 * 64 + lane]);
    float v2 = bf2f(hW[(size_t)s2 * 64 + lane]);
    float v3 = bf2f(hW[(size_t)s3 * 64 + lane]);
    if (relusrc) {
      v0 = fmaxf(v0, 0.f); v1 = fmaxf(v1, 0.f); v2 = fmaxf(v2, 0.f); v3 = fmaxf(v3, 0.f);
    }
    a += w0 * v0 + w1 * v1 + w2 * v2 + w3 * v3;
  }
  for (; i < i1; ++i) {
    int s = csr[i];
    float vv = bf2f(hW[(size_t)s * 64 + lane]);
    if (relusrc) vv = fmaxf(vv, 0.f);
    a += dd * dis[s] * vv;
  }
  agg[(size_t)d * 64 + lane] = __float2bfloat16(a);
}

// conv4: gather + bias + per-block mean-pool partial (plain stores); ILP-4
__global__ void agg_gather64_final_kernel(const bf16* __restrict__ hW, const int* __restrict__ rowstart,
                                          const int* __restrict__ csr, const float* __restrict__ dis,
                                          const void* __restrict__ b, const Ctl* __restrict__ ctl,
                                          float* __restrict__ partial, int M)
{
  __shared__ float cs[64];
  const bool f32 = ctl->isfp32 != 0;
  int tid = threadIdx.x;
  if (tid < 64) cs[tid] = 0.f;
  __syncthreads();
  int gid = blockIdx.x * 256 + tid;
  int d = gid >> 6;
  int lane = gid & 63;
  if (d < M) {
    float dd = dis[d];
    float a = bf2f(hW[(size_t)d * 64 + lane]) * (dd * dd) + loadF(b, lane, f32);
    int i = rowstart[d], i1 = rowstart[d + 1];
    for (; i + 4 <= i1; i += 4) {
      int s0 = csr[i], s1 = csr[i + 1], s2 = csr[i + 2], s3 = csr[i + 3];
      float w0 = dd * dis[s0], w1 = dd * dis[s1], w2 = dd * dis[s2], w3 = dd * dis[s3];
      float v0 = bf2f(hW[(size_t)s0 * 64 + lane]);
      float v1 = bf2f(hW[(size_t)s1 * 64 + lane]);
      float v2 = bf2f(hW[(size_t)s2 * 64 + lane]);
      float v3 = bf2f(hW[(size_t)s3 * 64 + lane]);
      a += w0 * v0 + w1 * v1 + w2 * v2 + w3 * v3;
    }
    for (; i < i1; ++i) {
      int s = csr[i];
      a += dd * dis[s] * bf2f(hW[(size_t)s * 64 + lane]);
    }
    atomicAdd(&cs[lane], a);
  }
  __syncthreads();
  if (tid < 64) partial[(size_t)tid * gridDim.x + blockIdx.x] = cs[tid];
}

__global__ void reduce_out_kernel(const float* __restrict__ partial, const Ctl* __restrict__ ctl,
                                  void* __restrict__ out, int nblk)
{
  __shared__ float sh[256];
  int c = blockIdx.x;
  float s = 0.f;
  for (int j = threadIdx.x; j < nblk; j += 256) s += partial[(size_t)c * nblk + j];
  sh[threadIdx.x] = s;
  __syncthreads();
  for (int st = 128; st > 0; st >>= 1) {
    if (threadIdx.x < st) sh[threadIdx.x] += sh[threadIdx.x + st];
    __syncthreads();
  }
  if (threadIdx.x == 0) {
    float val = sh[0] / (float)K_KEEP;
    if (ctl->isfp32) ((float*)out)[c] = val;
    else             ((bf16*)out)[c] = __float2bfloat16(val);
  }
}

// ---------------- TopK select (proven fused hist+pick) ----------------

__global__ void histpick_kernel(const u64* __restrict__ keys, Ctl* ctl, int shift, int nblocks) {
  __shared__ u32 lh[256];
  __shared__ int lastflag;
  const int tid = threadIdx.x;
  lh[tid] = 0;
  __syncthreads();
  u64 prefix = ctl->prefix;
  int i = blockIdx.x * 256 + tid;
  if (i < N_NODES) {
    u64 key = keys[i];
    if ((key >> (shift + 8)) == (prefix >> (shift + 8)))
      atomicAdd(&lh[(u32)((key >> shift) & 0xFF)], 1u);
  }
  __syncthreads();
  u32 c = lh[tid];
  if (c) atomicAdd(&ctl->hist[tid], c);
  __syncthreads();
  if (tid == 0) {
    __threadfence();
    u32 old = atomicAdd(&ctl->done, 1u);
    lastflag = (old == (u32)(nblocks - 1));
  }
  __syncthreads();
  if (!lastflag) return;
  lh[tid] = atomicExch(&ctl->hist[tid], 0u);
  __syncthreads();
  if (tid == 0) {
    u32 kr = ctl->kremain;
    u32 cum = 0;
    int sel = 0;
    for (int v = 255; v >= 0; --v) {
      u32 cc = lh[v];
      if (cum + cc >= kr) { sel = v; break; }
      cum += cc;
    }
    ctl->prefix = prefix | (((u64)sel) << shift);
    ctl->kremain = kr - cum;
    ctl->done = 0u;
  }
}

__global__ void mark_kernel(const u64* __restrict__ keys, Ctl* ctl,
                            int* __restrict__ new_idx, int* __restrict__ kept)
{
  int i = blockIdx.x * 256 + threadIdx.x;
  if (i >= N_NODES) return;
  if (keys[i] >= ctl->prefix) {
    int pos = (int)atomicAdd(&ctl->cnt, 1u);
    new_idx[i] = pos;
    kept[pos] = i;
  } else {
    new_idx[i] = -1;
  }
}

__global__ void hp_kernel(const bf16* __restrict__ h, const int* __restrict__ kept,
                          const float* __restrict__ score, bf16* __restrict__ hp)
{
  int gid = blockIdx.x * 256 + threadIdx.x;
  int row = gid >> 6;
  int lane = gid & 63;
  if (row >= K_KEEP) return;
  int o = kept[row];
  float s = score[o];
  bf16x2 v = ((const bf16x2*)h)[(size_t)o * 64 + lane];
  bf16x2 w;
  w.x = __float2bfloat16(fmaxf(bf2f(v.x), 0.f) * s);
  w.y = __float2bfloat16(fmaxf(bf2f(v.y), 0.f) * s);
  ((bf16x2*)hp)[(size_t)row * 64 + lane] = w;
}

// ---------------- launch ----------------

extern "C" void kernel_launch(void* const* d_in, const int* in_sizes, int n_in,
                              void* d_out, int out_size, void* d_ws, size_t ws_size,
                              hipStream_t stream)
{
  const void* x  = d_in[0];
  const int*  ei = (const int*)d_in[1];
  const void* W1 = d_in[3];
  const void* b1 = d_in[4];
  const void* pw = d_in[5];
  const void* W2 = d_in[6];
  const void* b2 = d_in[7];
  const void* W3 = d_in[8];
  const void* b3 = d_in[9];
  const void* W4 = d_in[10];
  const void* b4 = d_in[11];

  const int* src = ei;
  const int* dst = ei + N_EDGES;

  float* F = (float*)d_ws;
  bf16*  A16       = (bf16*)F;               // N x 128 bf16
  bf16*  B16       = (bf16*)(F + 3200000);   // N x 128 bf16
  bf16*  C16       = (bf16*)(F + 6400000);   // K x 128 bf16 (also conv1's G [N x 64])
  float* dis1      = F + 9000000;            // 50000
  float* dis2      = F + 9050000;            // 40000
  float* score     = F + 9100000;            // 50000
  u64*   keys      = (u64*)(F + 9150000);    // 50000 u64
  int*   new_idx   = (int*)(F + 9250000);    // 50000
  int*   kept      = (int*)(F + 9300000);    // 40000
  int*   cnt2      = (int*)(F + 9340000);    // 40000
  int*   rowstart1 = (int*)(F + 9380000);    // 50001
  int*   rowstart2 = (int*)(F + 9430004);    // 40001
  int*   csr1      = (int*)(F + 9470008);    // 800000
  int*   csr2      = (int*)(F + 10270008);   // 800000
  Ctl*   ctl       = (Ctl*)(F + 11070008);   // ~1.1 KB
  int*   bsum      = (int*)(F + 11070500);   // 256
  int*   boff      = (int*)(F + 11070756);   // 256
  int*   detcnt    = (int*)(F + 11071012);   // 64
  int*   bucket_cur= (int*)(F + 11071076);   // 196
  u32*   bucketbuf = (u32*)(F + 11071332);   // 196*6144
  float* partial   = F + 12275556;           // 64 x 10000

  const int NB1 = (N_NODES + 255) / 256;     // 196
  const int NB2 = (K_KEEP + 255) / 256;      // 157
  const int EB2 = (N_EDGES + 2047) / 2048;   // 391
  const int SGB = (K_KEEP * 16 + 255) / 256; // 2500
  const int GFB = K_KEEP / 4;                // 10000

  init_kernel<<<NB1, 256, 0, stream>>>((const unsigned short*)x, bucket_cur, detcnt, ctl);
  norm_kernel<<<1, 64, 0, stream>>>(pw, detcnt, ctl);

  // CSR graph 1 via bucket sort
  bucket_scatter_kernel<<<EB2, 256, 0, stream>>>(src, dst, bucket_cur, bucketbuf);
  scan_buckets_kernel<<<1, 256, 0, stream>>>(bucket_cur, boff, &rowstart1[N_NODES]);
  csr_from_buckets_kernel<<<BKT, 256, 0, stream>>>(bucketbuf, bucket_cur, boff, rowstart1, dis1, csr1);

  // conv1 (gather-first): G = A_norm . x ; h1 = G @ W1 + b1 (+fused score)
  agg_gather64_in_kernel<<<(N_NODES + 3) / 4, 256, 0, stream>>>(x, rowstart1, csr1, dis1, ctl, C16, N_NODES);
  gemm_in_kernel<<<(N_NODES + 63) / 64, 256, 0, stream>>>(C16, W1, b1, pw, B16, ctl, score, keys);

  // top-K select (6 x 8-bit radix over 48-bit keys)
  for (int p = 0; p < 6; ++p)
    histpick_kernel<<<NB1, 256, 0, stream>>>(keys, ctl, 40 - 8 * p, NB1);
  mark_kernel<<<NB1, 256, 0, stream>>>(keys, ctl, new_idx, kept);
  hp_kernel<<<(K_KEEP + 3) / 4, 256, 0, stream>>>(B16, kept, score, C16);

  // CSR graph 2: filter-compact kept rows of csr1
  cnt2_kernel<<<SGB, 256, 0, stream>>>(kept, rowstart1, csr1, new_idx, cnt2);
  block_reduce_kernel<<<NB2, 256, 0, stream>>>(cnt2, bsum, K_KEEP);
  scan_bsum_kernel<<<1, 256, 0, stream>>>(bsum, boff, NB2, &rowstart2[K_KEEP]);
  block_scanout_kernel<<<NB2, 256, 0, stream>>>(cnt2, boff, rowstart2, dis2, K_KEEP);
  fill2_kernel<<<SGB, 256, 0, stream>>>(kept, rowstart1, csr1, new_idx, rowstart2, csr2);

  // conv2: gemm-first: A = hp @ W2 ; h2 = gather(A) + b2
  gemm_128_64_kernel<<<K_KEEP / 64, 256, 0, stream>>>(C16, W2, A16, ctl, K_KEEP, 0);
  agg_gather64_kernel<<<K_KEEP / 4, 256, 0, stream>>>(A16, rowstart2, csr2, dis2, b2, ctl, B16, K_KEEP, 0, 1);

  // conv3: gather-first: G = gather(relu(h2)) ; h3 = G @ W3 + b3
  agg_gather64_kernel<<<K_KEEP / 4, 256, 0, stream>>>(B16, rowstart2, csr2, dis2, b3, ctl, A16, K_KEEP, 1, 0);
  gemm_64_128_kernel<<<K_KEEP / 64, 256, 0, stream>>>(A16, W3, b3, B16, ctl, K_KEEP);

  // conv4: gemm-first: A = relu(h3) @ W4 ; partials = gather(A) + b4
  gemm_128_64_kernel<<<K_KEEP / 64, 256, 0, stream>>>(B16, W4, A16, ctl, K_KEEP, 1);
  agg_gather64_final_kernel<<<GFB, 256, 0, stream>>>(A16, rowstart2, csr2, dis2, b4, ctl, partial, K_KEEP);

  reduce_out_kernel<<<64, 256, 0, stream>>>(partial, ctl, d_out, GFB);
}